// Round 10
// baseline (309.637 us; speedup 1.0000x reference)
//
#include <hip/hip_runtime.h>

// EfficientAttention: N=8, C=256, H=W=128 (L=16384), HEADS=8, hc=32
// out = x + att,  att[n,h,cv,l] = sum_ck (ctx[ck,cv]/S[ck]) * softmax_ck(q)[ck,l]
// ctx[ck,cv] = sum_l exp(k[ck,l]) * v[cv,l],  S[ck] = sum_l exp(k[ck,l])
//
// Toolchain law (R4-R9): the allocator will not hold large loop-invariant W
// fragments in VGPRs (caps ~88-128, remats global loads into the loop).
// => stream ALL MFMA operands from LDS; use 64x64 wave tiles (0.5 reads/MFMA).
// Wb row order (k_prep): tiles 0-3 = [h.k32|h.v32|h'.k32|h'.v32] (h=2t,2t+1),
// tiles 4-5 = q rows of heads 0-3 / 4-7  => every 128-row GEMM tile's epilogue
// is self-contained (ctx pairs + softmax classes never cross tiles).

typedef __attribute__((ext_vector_type(8))) short short8;
typedef __attribute__((ext_vector_type(4))) float f32x4;

#define NB     8
#define CCH    256
#define LSP    16384
#define NHEADS 8
#define HC     32

__device__ __forceinline__ unsigned short f2bf(float f) {
  union { float f; unsigned u; } v; v.f = f;
  unsigned r = v.u + 0x7fffu + ((v.u >> 16) & 1u);   // RNE
  return (unsigned short)(r >> 16);
}
__device__ __forceinline__ unsigned cvt_pk_bf16(float lo, float hi) {
  unsigned r;
  asm("v_cvt_pk_bf16_f32 %0, %1, %2" : "=v"(r) : "v"(lo), "v"(hi));
  return r;
}
__device__ __forceinline__ void gload_lds16(const unsigned short* g, unsigned short* l) {
  __builtin_amdgcn_global_load_lds(
      (const __attribute__((address_space(1))) unsigned int*)g,
      (__attribute__((address_space(3))) unsigned int*)l, 16, 0, 0);
}

// ---------------- kernel 0: weights -> bf16 tile-reordered rows, zero ctx/S ----------------
__global__ void k_prep(const float* __restrict__ Wk, const float* __restrict__ bk,
                       const float* __restrict__ Wq, const float* __restrict__ bq,
                       const float* __restrict__ Wv, const float* __restrict__ bv,
                       unsigned short* __restrict__ Wb, float* __restrict__ bb,
                       float* __restrict__ ctx, float* __restrict__ S) {
  int idx = blockIdx.x * 256 + threadIdx.x;
  if (idx < 768 * CCH) {
    int c = idx & 255, R = idx >> 8;
    const float* src; int d;
    if (R < 512) {
      int rt = R >> 7, w = R & 127;
      int h = 2 * rt + (w >> 6), s = w & 63;
      if (s < 32) { src = Wk; d = h * 32 + s; }
      else        { src = Wv; d = h * 32 + (s - 32); }
    } else {
      int R2 = R - 512;
      int h = (R2 >> 7) * 4 + ((R2 & 127) >> 5);
      src = Wq; d = h * 32 + (R2 & 31);
    }
    Wb[idx] = f2bf(src[d * 256 + c]);
  }
  if (idx < 768) {
    int R = idx;
    const float* src; int d;
    if (R < 512) {
      int rt = R >> 7, w = R & 127;
      int h = 2 * rt + (w >> 6), s = w & 63;
      if (s < 32) { src = bk; d = h * 32 + s; }
      else        { src = bv; d = h * 32 + (s - 32); }
    } else {
      int R2 = R - 512;
      int h = (R2 >> 7) * 4 + ((R2 & 127) >> 5);
      src = bq; d = h * 32 + (R2 & 31);
    }
    bb[R] = src[d];
  }
  if (idx < NB * NHEADS * HC * HC) ctx[idx] = 0.f;
  if (idx < NB * NHEADS * HC)      S[idx]   = 0.f;
}

// ---------------- kernel 0b: x [n][c][l] f32 -> xT [n][l][c] bf16 ----------------
__global__ __launch_bounds__(256)
void k_transpose(const float* __restrict__ x, unsigned short* __restrict__ xT) {
  __shared__ float tile[64][65];
  int b = blockIdx.x;
  int ct = b & 3;
  int lt = (b >> 2) & 255;
  int n  = b >> 10;
  int c0 = ct * 64, l0 = lt * 64;
  int t = threadIdx.x;
  int li = t & 63, cr = t >> 6;
  const float* xp = x + (size_t)n * CCH * LSP;
#pragma unroll
  for (int i = 0; i < 16; ++i) {
    int ci = cr * 16 + i;
    tile[ci][li] = xp[(size_t)(c0 + ci) * LSP + l0 + li];
  }
  __syncthreads();
  int cp = t & 31, l8 = t >> 5;
  unsigned short* xo = xT + ((size_t)n * LSP + l0) * CCH + c0;
#pragma unroll
  for (int i = 0; i < 8; ++i) {
    int l = l8 * 8 + i;
    unsigned pk = (unsigned)f2bf(tile[2 * cp][l]) | ((unsigned)f2bf(tile[2 * cp + 1][l]) << 16);
    *(unsigned*)&xo[(size_t)l * CCH + 2 * cp] = pk;
  }
}

// ---------------- kernel 1: fused QKV GEMM, 128x128 tiles, LDS-streamed operands ----------
// grid 6144 = 6 row-tiles x (8n x 128 px-tiles); bid = rt*1024 + n*128 + pxt
// (fixed (n,pxt) across rt differ by 1024 (mult of 8) -> same XCD -> x L2-shared).
// 256 thr = 4 waves (rh,ph in 2x2), wave tile 64 rows x 64 px, acc 64 VGPR.
// K=256 in 4 steps of 64; W-strip/x-strip [128][64] bf16 dbuf (64 KiB total) via
// global_load_lds, both-sides XOR chunk swizzle, counted vmcnt(8), 2 barriers/step.
// rt<4 (KV): swapped mfma(x,W) -> D[px][wrow]; exp/v -> wave-private strips
//   (overlaid on dead staging LDS) -> ctx mfma -> atomics once. S via shfl+atomic.
// rt>=4 (Q): mfma(W,x) -> D[qrow][px]; in-reg softmax over ck; b64 stores.
__global__ __launch_bounds__(256)
void k_fused(const unsigned short* __restrict__ xT,
             const unsigned short* __restrict__ Wb, const float* __restrict__ bb,
             unsigned short* __restrict__ qbuf, float* __restrict__ ctx,
             float* __restrict__ S) {
  __shared__ unsigned short lds[32768];   // 64 KiB: W0|W1|X0|X1 (8192 shorts each)

  int bid = (int)blockIdx.x;
  int rt = bid >> 10;
  int g = bid & 1023;
  int n = g >> 7, pxt = g & 127;
  int l0 = pxt << 7;
  int tid = threadIdx.x;
  int wid = tid >> 6, lane = tid & 63;
  int r16 = lane & 15, kg = lane >> 4;
  int rh = wid >> 1, ph = wid & 1;
  int sw = r16 & 7;

  const unsigned short* xTn = xT + (((size_t)n) << 14) * CCH;
  const unsigned short* Wrt = Wb + (size_t)rt * 128 * CCH;

  // stage one K-step strip pair into buffer b: per wave 4 W-pieces + 4 x-pieces
  // (piece = 8 rows x 128B). dest linear; source chunk-XOR-swizzled (rule 21).
  auto stage = [&](int b, int ks) {
#pragma unroll
    for (int i = 0; i < 4; ++i) {
      int f = wid * 4 + i;                  // 0..15
      int row = f * 8 + (lane >> 3);
      int ch = lane & 7;
      gload_lds16(Wrt + (size_t)row * CCH + ks * 64 + ((ch ^ (row & 7)) << 3),
                  lds + b * 8192 + f * 512);
    }
#pragma unroll
    for (int i = 0; i < 4; ++i) {
      int f = wid * 4 + i;
      int row = f * 8 + (lane >> 3);
      int ch = lane & 7;
      gload_lds16(xTn + (size_t)(l0 + row) * CCH + ks * 64 + ((ch ^ (row & 7)) << 3),
                  lds + 16384 + b * 8192 + f * 512);
    }
  };

  stage(0, 0);

  if (rt < 4) {
    // ================= KV tile =================
    int h = rt * 2 + rh;
    float bias[4];
#pragma unroll
    for (int j = 0; j < 4; ++j) bias[j] = bb[rt * 128 + rh * 64 + j * 16 + r16];

    f32x4 acc[4][4];   // [px-frag i][wrow-frag j]
#pragma unroll
    for (int i = 0; i < 4; ++i)
#pragma unroll
      for (int j = 0; j < 4; ++j) acc[i][j] = (f32x4){0.f, 0.f, 0.f, 0.f};

    for (int ks = 0; ks < 4; ++ks) {
      if (ks) __builtin_amdgcn_s_barrier();            // all waves done compute(ks-1)
      if (ks + 1 < 4) stage((ks + 1) & 1, ks + 1);
      __builtin_amdgcn_sched_barrier(0);
      if (ks + 1 < 4) { asm volatile("s_waitcnt vmcnt(8)" ::: "memory"); }
      else            { asm volatile("s_waitcnt vmcnt(0)" ::: "memory"); }
      __builtin_amdgcn_sched_barrier(0);
      __builtin_amdgcn_s_barrier();                    // buf[ks] fully staged
      const unsigned short* wl = lds + (ks & 1) * 8192;
      const unsigned short* xl = lds + 16384 + (ks & 1) * 8192;
#pragma unroll
      for (int kkk = 0; kkk < 2; ++kkk) {
        int co = (((kkk * 4 + kg) ^ sw) << 3);
        short8 wf[4], xf[4];
#pragma unroll
        for (int j = 0; j < 4; ++j)
          wf[j] = *(const short8*)&wl[(rh * 64 + j * 16 + r16) * 64 + co];
#pragma unroll
        for (int i = 0; i < 4; ++i)
          xf[i] = *(const short8*)&xl[(ph * 64 + i * 16 + r16) * 64 + co];
#pragma unroll
        for (int i = 0; i < 4; ++i)
#pragma unroll
          for (int j = 0; j < 4; ++j)
            acc[i][j] = __builtin_amdgcn_mfma_f32_16x16x32_bf16(xf[i], wf[j], acc[i][j], 0, 0, 0);
      }
    }
    __builtin_amdgcn_s_barrier();     // staging dead -> strips may overlay lds

    // scatter: lane holds (wrow = j*16+r16, px = i*16+kg*4+r); strips [kind][32][72]
    unsigned short* st = lds + wid * 4608;
    float sk0 = 0.f, sk1 = 0.f;
#pragma unroll
    for (int i = 0; i < 4; ++i)
#pragma unroll
      for (int j = 0; j < 4; ++j) {
        float v0 = acc[i][j][0] + bias[j];
        float v1 = acc[i][j][1] + bias[j];
        float v2 = acc[i][j][2] + bias[j];
        float v3 = acc[i][j][3] + bias[j];
        if (j < 2) {
          float e0 = __expf(v0), e1 = __expf(v1), e2 = __expf(v2), e3 = __expf(v3);
          if (j == 0) sk0 += e0 + e1 + e2 + e3; else sk1 += e0 + e1 + e2 + e3;
          uint2 u = {cvt_pk_bf16(e0, e1), cvt_pk_bf16(e2, e3)};
          *(uint2*)&st[(j * 16 + r16) * 72 + i * 16 + kg * 4] = u;
        } else {
          uint2 u = {cvt_pk_bf16(v0, v1), cvt_pk_bf16(v2, v3)};
          *(uint2*)&st[(32 + (j - 2) * 16 + r16) * 72 + i * 16 + kg * 4] = u;
        }
      }
    // ctx = ek (32 x 64px) . v^T  (wave-private strips, same-wave ds ordering)
    f32x4 actx[2][2];
#pragma unroll
    for (int a = 0; a < 2; ++a)
#pragma unroll
      for (int b = 0; b < 2; ++b) actx[a][b] = (f32x4){0.f, 0.f, 0.f, 0.f};
#pragma unroll
    for (int ckf = 0; ckf < 2; ++ckf)
#pragma unroll
      for (int cvf = 0; cvf < 2; ++cvf)
#pragma unroll
        for (int kkp = 0; kkp < 2; ++kkp) {
          short8 ek = *(const short8*)&st[(ckf * 16 + r16) * 72 + kkp * 32 + kg * 8];
          short8 vv = *(const short8*)&st[(32 + cvf * 16 + r16) * 72 + kkp * 32 + kg * 8];
          actx[ckf][cvf] = __builtin_amdgcn_mfma_f32_16x16x32_bf16(ek, vv, actx[ckf][cvf], 0, 0, 0);
        }
    float* cp = ctx + ((size_t)(n * NHEADS + h) << 10);
#pragma unroll
    for (int ckf = 0; ckf < 2; ++ckf)
#pragma unroll
      for (int cvf = 0; cvf < 2; ++cvf)
#pragma unroll
        for (int r = 0; r < 4; ++r)
          atomicAdd(&cp[(ckf * 16 + kg * 4 + r) * HC + cvf * 16 + r16], actx[ckf][cvf][r]);
    {
      float s0 = sk0, s1 = sk1;
      s0 += __shfl_xor(s0, 16); s0 += __shfl_xor(s0, 32);
      s1 += __shfl_xor(s1, 16); s1 += __shfl_xor(s1, 32);
      if (kg == 0) {
        atomicAdd(&S[(n * NHEADS + h) * HC + r16], s0);
        atomicAdd(&S[(n * NHEADS + h) * HC + 16 + r16], s1);
      }
    }
  } else {
    // ================= Q tile =================
    int hb4 = (rt - 4) * 4 + rh * 2;    // head base for this wave's two 32-row classes
    float bias[4][4];
#pragma unroll
    for (int m = 0; m < 4; ++m)
#pragma unroll
      for (int r = 0; r < 4; ++r)
        bias[m][r] = bb[512 + (rt - 4) * 128 + rh * 64 + m * 16 + kg * 4 + r];

    f32x4 acc[4][4];   // [qrow-frag m][px-frag p]
#pragma unroll
    for (int m = 0; m < 4; ++m)
#pragma unroll
      for (int p = 0; p < 4; ++p) acc[m][p] = (f32x4){0.f, 0.f, 0.f, 0.f};

    for (int ks = 0; ks < 4; ++ks) {
      if (ks) __builtin_amdgcn_s_barrier();
      if (ks + 1 < 4) stage((ks + 1) & 1, ks + 1);
      __builtin_amdgcn_sched_barrier(0);
      if (ks + 1 < 4) { asm volatile("s_waitcnt vmcnt(8)" ::: "memory"); }
      else            { asm volatile("s_waitcnt vmcnt(0)" ::: "memory"); }
      __builtin_amdgcn_sched_barrier(0);
      __builtin_amdgcn_s_barrier();
      const unsigned short* wl = lds + (ks & 1) * 8192;
      const unsigned short* xl = lds + 16384 + (ks & 1) * 8192;
#pragma unroll
      for (int kkk = 0; kkk < 2; ++kkk) {
        int co = (((kkk * 4 + kg) ^ sw) << 3);
        short8 wf[4], xf[4];
#pragma unroll
        for (int m = 0; m < 4; ++m)
          wf[m] = *(const short8*)&wl[(rh * 64 + m * 16 + r16) * 64 + co];
#pragma unroll
        for (int p = 0; p < 4; ++p)
          xf[p] = *(const short8*)&xl[(ph * 64 + p * 16 + r16) * 64 + co];
#pragma unroll
        for (int m = 0; m < 4; ++m)
#pragma unroll
          for (int p = 0; p < 4; ++p)
            acc[m][p] = __builtin_amdgcn_mfma_f32_16x16x32_bf16(wf[m], xf[p], acc[m][p], 0, 0, 0);
      }
    }
    // softmax over ck per px (8 in-lane + 2 shfl over kg); store [l][ck] b64
#pragma unroll
    for (int p = 0; p < 4; ++p) {
#pragma unroll
      for (int hm = 0; hm < 2; ++hm) {
        float e0[4], e1[4];
        float s = 0.f;
#pragma unroll
        for (int r = 0; r < 4; ++r) {
          e0[r] = __expf(acc[hm * 2][p][r] + bias[hm * 2][r]);
          e1[r] = __expf(acc[hm * 2 + 1][p][r] + bias[hm * 2 + 1][r]);
          s += e0[r] + e1[r];
        }
        s += __shfl_xor(s, 16);
        s += __shfl_xor(s, 32);
        float inv = 1.f / s;
        int hq = hb4 + hm;
        int l = l0 + ph * 64 + p * 16 + r16;
        unsigned short* qb = qbuf + (((size_t)(n * NHEADS + hq) * LSP + l) << 5);
        uint2 u0 = {cvt_pk_bf16(e0[0] * inv, e0[1] * inv), cvt_pk_bf16(e0[2] * inv, e0[3] * inv)};
        uint2 u1 = {cvt_pk_bf16(e1[0] * inv, e1[1] * inv), cvt_pk_bf16(e1[2] * inv, e1[3] * inv)};
        *(uint2*)&qb[kg * 4]      = u0;
        *(uint2*)&qb[16 + kg * 4] = u1;
      }
    }
  }
}

// ---------------- kernel 2: ctx/S, transpose, -> bf16 ----------------
__global__ void k_norm(const float* __restrict__ ctx, const float* __restrict__ S,
                       unsigned short* __restrict__ ctxT) {
  int idx = blockIdx.x * 256 + threadIdx.x;  // 65536 = [n][h][ck][cv]
  int cv = idx & 31, ck = (idx >> 5) & 31, nh = idx >> 10;
  float v = ctx[idx] / S[(nh << 5) + ck];
  ctxT[(nh << 10) + (cv << 5) + ck] = f2bf(v);
}

// ---------------- kernel 3: att = ctxT (32x32) x q_soft (32 x L) + residual ----------------
__global__ __launch_bounds__(256)
void k_att(const float* __restrict__ x, const unsigned short* __restrict__ qbuf,
           const unsigned short* __restrict__ ctxT, float* __restrict__ out) {
  int b = blockIdx.x;
  int lc = b & 63;
  int nh = b >> 6;
  int h = nh & 7, n = nh >> 3;
  int tid = threadIdx.x, wid = tid >> 6, lane = tid & 63;
  int r16 = lane & 15, kg = lane >> 4;
  int lw = lc * 256 + wid * 64;

  const unsigned short* cp = ctxT + ((size_t)nh << 10);
  short8 a0 = *(const short8*)&cp[(r16 << 5) + kg * 8];          // A[cv][ck], cv 0-15
  short8 a1 = *(const short8*)&cp[((16 + r16) << 5) + kg * 8];   // cv 16-31
  const unsigned short* qb = qbuf + (((size_t)nh * LSP) << 5);
  const float* xp = x   + ((size_t)n * CCH + (size_t)h * HC) * LSP;
  float*       op = out + ((size_t)n * CCH + (size_t)h * HC) * LSP;

#pragma unroll
  for (int t = 0; t < 4; ++t) {
    int l = lw + t * 16;
    short8 bf = *(const short8*)&qb[((size_t)(l + r16) << 5) + kg * 8];  // softmaxed q [l][ck]
    f32x4 d0 = {0, 0, 0, 0}, d1 = {0, 0, 0, 0};
    d0 = __builtin_amdgcn_mfma_f32_16x16x32_bf16(a0, bf, d0, 0, 0, 0);
    d1 = __builtin_amdgcn_mfma_f32_16x16x32_bf16(a1, bf, d1, 0, 0, 0);
#pragma unroll
    for (int r = 0; r < 4; ++r) {
      int cv = kg * 4 + r;
      int li = l + r16;
      op[(size_t)cv * LSP + li]        = d0[r] + xp[(size_t)cv * LSP + li];
      op[(size_t)(cv + 16) * LSP + li] = d1[r] + xp[(size_t)(cv + 16) * LSP + li];
    }
  }
}

extern "C" void kernel_launch(void* const* d_in, const int* in_sizes, int n_in,
                              void* d_out, int out_size, void* d_ws, size_t ws_size,
                              hipStream_t stream) {
  (void)in_sizes; (void)n_in; (void)out_size; (void)ws_size;
  const float* x  = (const float*)d_in[0];
  const float* Wk = (const float*)d_in[1];
  const float* bk = (const float*)d_in[2];
  const float* Wq = (const float*)d_in[3];
  const float* bq = (const float*)d_in[4];
  const float* Wv = (const float*)d_in[5];
  const float* bv = (const float*)d_in[6];
  float* out = (float*)d_out;

  char* ws = (char*)d_ws;
  unsigned short* Wb   = (unsigned short*)(ws + 0);          //   393216
  float*          bbp  = (float*)(ws + 393216);              //     3072
  float*          ctx  = (float*)(ws + 396288);              //   262144
  unsigned short* ctxT = (unsigned short*)(ws + 658432);     //   131072
  float*          S    = (float*)(ws + 789504);              //     8192
  unsigned short* qbuf = (unsigned short*)(ws + 797696);     // 67108864
  unsigned short* xT   = (unsigned short*)(ws + 67906560);   // 67108864 -> 135015424 total

  k_prep<<<768, 256, 0, stream>>>(Wk, bk, Wq, bq, Wv, bv, Wb, bbp, ctx, S);
  k_transpose<<<NB * 256 * 4, 256, 0, stream>>>(x, xT);
  k_fused<<<6144, 256, 0, stream>>>(xT, Wb, bbp, qbuf, ctx, S);
  k_norm<<<256, 256, 0, stream>>>(ctx, S, ctxT);
  k_att<<<NB * NHEADS * 64, 256, 0, stream>>>(x, qbuf, ctxT, out);
}

// Round 11
// 229.050 us; speedup vs baseline: 1.3518x; 1.3518x over previous
//
#include <hip/hip_runtime.h>

// EfficientAttention: N=8, C=256, H=W=128 (L=16384), HEADS=8, hc=32
// out = x + att,  att[n,h,cv,l] = sum_ck (ctx[ck,cv]/S[ck]) * softmax_ck(q)[ck,l]
// ctx[ck,cv] = sum_l exp(k[ck,l]) * v[cv,l],  S[ck] = sum_l exp(k[ck,l])
//
// Toolchain law (R4-R10): VGPR allocation is erratic (84-148); any wave needing
// >~80 live regs risks spill/remat. This design: all MFMA operands streamed from
// LDS, acc = 24 regs, live set ~65. One head/block, W-LDS staged once.

typedef __attribute__((ext_vector_type(8))) short short8;
typedef __attribute__((ext_vector_type(4))) float f32x4;

#define NB     8
#define CCH    256
#define LSP    16384
#define NHEADS 8
#define HC     32

__device__ __forceinline__ unsigned short f2bf(float f) {
  union { float f; unsigned u; } v; v.f = f;
  unsigned r = v.u + 0x7fffu + ((v.u >> 16) & 1u);   // RNE
  return (unsigned short)(r >> 16);
}
__device__ __forceinline__ unsigned cvt_pk_bf16(float lo, float hi) {
  unsigned r;
  asm("v_cvt_pk_bf16_f32 %0, %1, %2" : "=v"(r) : "v"(lo), "v"(hi));
  return r;
}
__device__ __forceinline__ void gload_lds16(const unsigned short* g, unsigned short* l) {
  __builtin_amdgcn_global_load_lds(
      (const __attribute__((address_space(1))) unsigned int*)g,
      (__attribute__((address_space(3))) unsigned int*)l, 16, 0, 0);
}

// ---------------- kernel 0: weights -> bf16 head-grouped [k32|v32|q32], zero ctx/S --------
__global__ void k_prep(const float* __restrict__ Wk, const float* __restrict__ bk,
                       const float* __restrict__ Wq, const float* __restrict__ bq,
                       const float* __restrict__ Wv, const float* __restrict__ bv,
                       unsigned short* __restrict__ Wb, float* __restrict__ bb,
                       float* __restrict__ ctx, float* __restrict__ S) {
  int idx = blockIdx.x * 256 + threadIdx.x;
  if (idx < NHEADS * 96 * CCH) {
    int c = idx & (CCH - 1);
    int row = (idx >> 8) % 96;
    int h = idx / (96 * CCH);
    int ch = h * HC;
    float val;
    if (row < HC)          val = Wk[(ch + row) * CCH + c];
    else if (row < 2 * HC) val = Wv[(ch + row - HC) * CCH + c];
    else                   val = Wq[(ch + row - 2 * HC) * CCH + c];
    Wb[idx] = f2bf(val);
  }
  if (idx < NHEADS * 96) {
    int row = idx % 96, h = idx / 96, ch = h * HC;
    float val;
    if (row < HC)          val = bk[ch + row];
    else if (row < 2 * HC) val = bv[ch + row - HC];
    else                   val = bq[ch + row - 2 * HC];
    bb[idx] = val;
  }
  if (idx < NB * NHEADS * HC * HC) ctx[idx] = 0.f;
  if (idx < NB * NHEADS * HC)      S[idx]   = 0.f;
}

// ---------------- kernel 0b: x [n][c][l] f32 -> xT [n][l][c] bf16 ----------------
__global__ __launch_bounds__(256)
void k_transpose(const float* __restrict__ x, unsigned short* __restrict__ xT) {
  __shared__ float tile[64][65];
  int b = blockIdx.x;
  int ct = b & 3;
  int lt = (b >> 2) & 255;
  int n  = b >> 10;
  int c0 = ct * 64, l0 = lt * 64;
  int t = threadIdx.x;
  int li = t & 63, cr = t >> 6;
  const float* xp = x + (size_t)n * CCH * LSP;
#pragma unroll
  for (int i = 0; i < 16; ++i) {
    int ci = cr * 16 + i;
    tile[ci][li] = xp[(size_t)(c0 + ci) * LSP + l0 + li];
  }
  __syncthreads();
  int cp = t & 31, l8 = t >> 5;
  unsigned short* xo = xT + ((size_t)n * LSP + l0) * CCH + c0;
#pragma unroll
  for (int i = 0; i < 8; ++i) {
    int l = l8 * 8 + i;
    unsigned pk = (unsigned)f2bf(tile[2 * cp][l]) | ((unsigned)f2bf(tile[2 * cp + 1][l]) << 16);
    *(unsigned*)&xo[(size_t)l * CCH + 2 * cp] = pk;
  }
}

// ---------------- kernel 1: fused QKV, one head/block, LDS-streamed W ----------------
// grid 1024: bid = c + 128*h (c = n*16 + chunk) -> 8 h-siblings of a chunk share an
// XCD in adjacent rounds -> x HBM-fetched once, L2-served 7x. 512 thr = 8 waves
// (2 row-halves rh x 4 px-quarters pq). Per kk: 3 W-frags + 2 x-frags -> 6 MFMA:
//   KV swapped mfma(x,W): lane = (4 contig px, 1 wrow) -> uint2 strip writes
//   Q  normal mfma(W,x): lane = (4 contig ck, 1 px)  -> in-reg softmax, uint2 stores
// ctx: each wave MFMAs exactly the strip region it wrote (same rh, same pq) -> no
// cross-wave hazard; atomics once per block. Single-buffer x-tile; stage(t+1) DMA
// issued before the epilogue, drained at tile end.
__global__ __launch_bounds__(512)
void k_fused(const unsigned short* __restrict__ xT,
             const unsigned short* __restrict__ Wb, const float* __restrict__ bb,
             unsigned short* __restrict__ qbuf, float* __restrict__ ctx,
             float* __restrict__ S) {
  __shared__ unsigned short wlds[96 * 256];   // 48 KiB
  __shared__ unsigned short xt[128 * 256];    // 64 KiB
  __shared__ unsigned short ekst[32][136];    // 8.5 KiB  exp(k) strips [krow][px]
  __shared__ unsigned short vst[32][136];     // 8.5 KiB  v strips [vrow][px]
  __shared__ float qs[2][128];                // 1 KiB    per-half q exp-sums [rh][px]

  int bid = (int)blockIdx.x;
  int h = bid >> 7, c = bid & 127;
  int n = c >> 4, chunk = c & 15;
  int l0 = chunk << 10;                       // 1024-px chunk
  int tid = threadIdx.x;
  int wid = tid >> 6, lane = tid & 63;
  int r16 = lane & 15, kg = lane >> 4;
  int rh = wid & 1, pq = wid >> 1;
  int px0 = pq * 32;

  const unsigned short* xTn = xT + ((size_t)n << 14) * CCH;
  const unsigned short* Wh = Wb + (size_t)h * 96 * CCH;

  // stage x tile tt (128 px x 256 ch): 64 pieces of 1 KiB, 8 per wave.
  // dest linear; source chunk-XOR-swizzled (both-sides involution, rule 21)
  auto stage_xt = [&](int tt) {
    int lb = l0 + tt * 128;
#pragma unroll
    for (int i = 0; i < 8; ++i) {
      int p = wid * 8 + i;                    // 0..63
      int px = p * 2 + (lane >> 5);
      int ch = lane & 31;
      gload_lds16(xTn + ((size_t)(lb + px) << 8) + ((ch ^ (px & 7)) << 3),
                  xt + p * 512);
    }
  };

  // prologue: W (48 pieces, 6/wave) + first x tile
  {
#pragma unroll
    for (int i = 0; i < 6; ++i) {
      int p = wid * 6 + i;                    // 0..47
      int row = p * 2 + (lane >> 5);
      int ch = lane & 31;
      gload_lds16(Wh + ((size_t)row << 8) + ((ch ^ (row & 7)) << 3), wlds + p * 512);
    }
    stage_xt(0);
  }

  float bkv0 = bb[h * 96 + rh * 16 + r16];
  float bkv1 = bb[h * 96 + 32 + rh * 16 + r16];
  float bq[4];
#pragma unroll
  for (int r = 0; r < 4; ++r) bq[r] = bb[h * 96 + 64 + rh * 16 + kg * 4 + r];

  f32x4 acc_ctx[2] = {{0.f,0.f,0.f,0.f},{0.f,0.f,0.f,0.f}};
  float sk = 0.f;

  asm volatile("s_waitcnt vmcnt(0)" ::: "memory");
  __builtin_amdgcn_sched_barrier(0);
  __builtin_amdgcn_s_barrier();
  __builtin_amdgcn_sched_barrier(0);

  for (int t = 0; t < 8; ++t) {
    // ---- K-loop: 96x(32px) via 6 MFMA per kk from 5 LDS reads ----
    f32x4 akv[2][2], aq[2];
#pragma unroll
    for (int j = 0; j < 2; ++j) { akv[j][0] = (f32x4){0,0,0,0}; akv[j][1] = (f32x4){0,0,0,0}; }
    aq[0] = (f32x4){0,0,0,0}; aq[1] = (f32x4){0,0,0,0};
#pragma unroll
    for (int kk = 0; kk < 8; ++kk) {
      int co = (((kk * 4 + kg) ^ (r16 & 7)) << 3);
      short8 w0 = *(const short8*)&wlds[(rh * 16 + r16) * 256 + co];         // k rows
      short8 w1 = *(const short8*)&wlds[(32 + rh * 16 + r16) * 256 + co];    // v rows
      short8 w2 = *(const short8*)&wlds[(64 + rh * 16 + r16) * 256 + co];    // q rows
      short8 x0 = *(const short8*)&xt[(px0 + r16) * 256 + co];
      short8 x1 = *(const short8*)&xt[(px0 + 16 + r16) * 256 + co];
      akv[0][0] = __builtin_amdgcn_mfma_f32_16x16x32_bf16(x0, w0, akv[0][0], 0, 0, 0);
      akv[0][1] = __builtin_amdgcn_mfma_f32_16x16x32_bf16(x1, w0, akv[0][1], 0, 0, 0);
      akv[1][0] = __builtin_amdgcn_mfma_f32_16x16x32_bf16(x0, w1, akv[1][0], 0, 0, 0);
      akv[1][1] = __builtin_amdgcn_mfma_f32_16x16x32_bf16(x1, w1, akv[1][1], 0, 0, 0);
      aq[0]     = __builtin_amdgcn_mfma_f32_16x16x32_bf16(w2, x0, aq[0], 0, 0, 0);
      aq[1]     = __builtin_amdgcn_mfma_f32_16x16x32_bf16(w2, x1, aq[1], 0, 0, 0);
    }
    __builtin_amdgcn_s_barrier();            // all waves done reading xt
    if (t + 1 < 8) stage_xt(t + 1);          // DMA flies under epilogue

    // ---- epilogue A: KV scatter (swapped: lane = 4 contig px, wrow rh*16+r16) ----
#pragma unroll
    for (int p = 0; p < 2; ++p) {
      {  // k -> exp -> strip + S
        float e0 = __expf(akv[0][p][0] + bkv0), e1 = __expf(akv[0][p][1] + bkv0);
        float e2 = __expf(akv[0][p][2] + bkv0), e3 = __expf(akv[0][p][3] + bkv0);
        sk += e0 + e1 + e2 + e3;
        uint2 u = {cvt_pk_bf16(e0, e1), cvt_pk_bf16(e2, e3)};
        *(uint2*)&ekst[rh * 16 + r16][px0 + p * 16 + kg * 4] = u;
      }
      {  // v -> strip
        float v0 = akv[1][p][0] + bkv1, v1 = akv[1][p][1] + bkv1;
        float v2 = akv[1][p][2] + bkv1, v3 = akv[1][p][3] + bkv1;
        uint2 u = {cvt_pk_bf16(v0, v1), cvt_pk_bf16(v2, v3)};
        *(uint2*)&vst[rh * 16 + r16][px0 + p * 16 + kg * 4] = u;
      }
    }
    // ---- epilogue A: Q exp + half-sums (normal: lane = 4 contig ck, px per p) ----
    float eq[2][4];
#pragma unroll
    for (int p = 0; p < 2; ++p) {
      float s = 0.f;
#pragma unroll
      for (int r = 0; r < 4; ++r) {
        eq[p][r] = __expf(aq[p][r] + bq[r]);
        s += eq[p][r];
      }
      s += __shfl_xor(s, 16);
      s += __shfl_xor(s, 32);                // sum over this rh-half's 16 ck
      if (kg == 0) qs[rh][px0 + p * 16 + r16] = s;
    }
    asm volatile("s_waitcnt lgkmcnt(0)" ::: "memory");
    __builtin_amdgcn_sched_barrier(0);
    __builtin_amdgcn_s_barrier();            // qs cross-wave visible

    // ---- epilogue B: ctx MFMA on own strips (K = own pq's 32 px) ----
    {
      short8 a = *(const short8*)&ekst[rh * 16 + r16][px0 + kg * 8];
      short8 b0 = *(const short8*)&vst[r16][px0 + kg * 8];
      short8 b1 = *(const short8*)&vst[16 + r16][px0 + kg * 8];
      acc_ctx[0] = __builtin_amdgcn_mfma_f32_16x16x32_bf16(a, b0, acc_ctx[0], 0, 0, 0);
      acc_ctx[1] = __builtin_amdgcn_mfma_f32_16x16x32_bf16(a, b1, acc_ctx[1], 0, 0, 0);
    }
    // ---- epilogue B: q normalize + store [l][ck] ----
#pragma unroll
    for (int p = 0; p < 2; ++p) {
      int px = px0 + p * 16 + r16;
      float inv = 1.f / (qs[0][px] + qs[1][px]);
      uint2 u = {cvt_pk_bf16(eq[p][0] * inv, eq[p][1] * inv),
                 cvt_pk_bf16(eq[p][2] * inv, eq[p][3] * inv)};
      size_t l = (size_t)l0 + t * 128 + px;
      *(uint2*)&qbuf[(((size_t)(n * NHEADS + h) * LSP + l) << 5) + rh * 16 + kg * 4] = u;
    }
    if (t + 1 < 8) {
      __builtin_amdgcn_sched_barrier(0);
      asm volatile("s_waitcnt vmcnt(2)" ::: "memory");   // stage done; 2 q-stores linger
      __builtin_amdgcn_sched_barrier(0);
      __builtin_amdgcn_s_barrier();
      __builtin_amdgcn_sched_barrier(0);
    }
  }

  // ---- flush: ctx quadrants (per wave: rows rh-half, K was pq-chunk) + S ----
  float* cp = ctx + ((size_t)(n * NHEADS + h) << 10);
#pragma unroll
  for (int cvf = 0; cvf < 2; ++cvf)
#pragma unroll
    for (int r = 0; r < 4; ++r)
      atomicAdd(&cp[(rh * 16 + kg * 4 + r) * HC + cvf * 16 + r16], acc_ctx[cvf][r]);
  {
    float s = sk;
    s += __shfl_xor(s, 16);
    s += __shfl_xor(s, 32);                  // sum over kg (px groups)
    if (kg == 0) atomicAdd(&S[(n * NHEADS + h) * HC + rh * 16 + r16], s);
  }
}

// ---------------- kernel 2: ctx/S, transpose, -> bf16 ----------------
__global__ void k_norm(const float* __restrict__ ctx, const float* __restrict__ S,
                       unsigned short* __restrict__ ctxT) {
  int idx = blockIdx.x * 256 + threadIdx.x;  // 65536 = [n][h][ck][cv]
  int cv = idx & 31, ck = (idx >> 5) & 31, nh = idx >> 10;
  float v = ctx[idx] / S[(nh << 5) + ck];
  ctxT[(nh << 10) + (cv << 5) + ck] = f2bf(v);
}

// ---------------- kernel 3: att = ctxT (32x32) x q_soft (32 x L) + residual ----------------
__global__ __launch_bounds__(256)
void k_att(const float* __restrict__ x, const unsigned short* __restrict__ qbuf,
           const unsigned short* __restrict__ ctxT, float* __restrict__ out) {
  int b = blockIdx.x;
  int lc = b & 63;
  int nh = b >> 6;
  int h = nh & 7, n = nh >> 3;
  int tid = threadIdx.x, wid = tid >> 6, lane = tid & 63;
  int r16 = lane & 15, kg = lane >> 4;
  int lw = lc * 256 + wid * 64;

  const unsigned short* cp = ctxT + ((size_t)nh << 10);
  short8 a0 = *(const short8*)&cp[(r16 << 5) + kg * 8];          // A[cv][ck], cv 0-15
  short8 a1 = *(const short8*)&cp[((16 + r16) << 5) + kg * 8];   // cv 16-31
  const unsigned short* qb = qbuf + (((size_t)nh * LSP) << 5);
  const float* xp = x   + ((size_t)n * CCH + (size_t)h * HC) * LSP;
  float*       op = out + ((size_t)n * CCH + (size_t)h * HC) * LSP;

#pragma unroll
  for (int t = 0; t < 4; ++t) {
    int l = lw + t * 16;
    short8 bf = *(const short8*)&qb[((size_t)(l + r16) << 5) + kg * 8];  // softmaxed q [l][ck]
    f32x4 d0 = {0, 0, 0, 0}, d1 = {0, 0, 0, 0};
    d0 = __builtin_amdgcn_mfma_f32_16x16x32_bf16(a0, bf, d0, 0, 0, 0);
    d1 = __builtin_amdgcn_mfma_f32_16x16x32_bf16(a1, bf, d1, 0, 0, 0);
#pragma unroll
    for (int r = 0; r < 4; ++r) {
      int cv = kg * 4 + r;
      int li = l + r16;
      op[(size_t)cv * LSP + li]        = d0[r] + xp[(size_t)cv * LSP + li];
      op[(size_t)(cv + 16) * LSP + li] = d1[r] + xp[(size_t)(cv + 16) * LSP + li];
    }
  }
}

extern "C" void kernel_launch(void* const* d_in, const int* in_sizes, int n_in,
                              void* d_out, int out_size, void* d_ws, size_t ws_size,
                              hipStream_t stream) {
  (void)in_sizes; (void)n_in; (void)out_size; (void)ws_size;
  const float* x  = (const float*)d_in[0];
  const float* Wk = (const float*)d_in[1];
  const float* bk = (const float*)d_in[2];
  const float* Wq = (const float*)d_in[3];
  const float* bq = (const float*)d_in[4];
  const float* Wv = (const float*)d_in[5];
  const float* bv = (const float*)d_in[6];
  float* out = (float*)d_out;

  char* ws = (char*)d_ws;
  unsigned short* Wb   = (unsigned short*)(ws + 0);          //   393216
  float*          bbp  = (float*)(ws + 393216);              //     3072
  float*          ctx  = (float*)(ws + 396288);              //   262144
  unsigned short* ctxT = (unsigned short*)(ws + 658432);     //   131072
  float*          S    = (float*)(ws + 789504);              //     8192
  unsigned short* qbuf = (unsigned short*)(ws + 797696);     // 67108864
  unsigned short* xT   = (unsigned short*)(ws + 67906560);   // 67108864 -> 135015424 total

  k_prep<<<768, 256, 0, stream>>>(Wk, bk, Wq, bq, Wv, bv, Wb, bbp, ctx, S);
  k_transpose<<<NB * 256 * 4, 256, 0, stream>>>(x, xT);
  k_fused<<<1024, 512, 0, stream>>>(xT, Wb, bbp, qbuf, ctx, S);
  k_norm<<<256, 256, 0, stream>>>(ctx, S, ctxT);
  k_att<<<NB * NHEADS * 64, 256, 0, stream>>>(x, qbuf, ctxT, out);
}

// Round 12
// 217.541 us; speedup vs baseline: 1.4234x; 1.0529x over previous
//
#include <hip/hip_runtime.h>

// EfficientAttention: N=8, C=256, H=W=128 (L=16384), HEADS=8, hc=32
// out = x + att,  att[n,h,cv,l] = sum_ck (ctx[ck,cv]/S[ck]) * softmax_ck(q)[ck,l]
// ctx[ck,cv] = sum_l exp(k[ck,l]) * v[cv,l],  S[ck] = sum_l exp(k[ck,l])
//
// k_fused design (R12): LDS-port is the wall (R11: 2.7M b128 reads = 51us port).
// 48x64 wave tiles (7 reads -> 12 MFMA) cut reads to 1.9M (~37us). 1 block/CU,
// W staged once per CU, 2 barriers/tile, wave-local epilogues (q softmax wholly
// inside rh1 waves), strip double-buffer with ctx-MFMA pipelined one tile behind.

typedef __attribute__((ext_vector_type(8))) short short8;
typedef __attribute__((ext_vector_type(4))) float f32x4;

#define NB     8
#define CCH    256
#define LSP    16384
#define NHEADS 8
#define HC     32
#define NT     32     // 128-px tiles per block (4096-px quarter-L)

__device__ __forceinline__ unsigned short f2bf(float f) {
  union { float f; unsigned u; } v; v.f = f;
  unsigned r = v.u + 0x7fffu + ((v.u >> 16) & 1u);   // RNE
  return (unsigned short)(r >> 16);
}
__device__ __forceinline__ unsigned cvt_pk_bf16(float lo, float hi) {
  unsigned r;
  asm("v_cvt_pk_bf16_f32 %0, %1, %2" : "=v"(r) : "v"(lo), "v"(hi));
  return r;
}
__device__ __forceinline__ void gload_lds16(const unsigned short* g, unsigned short* l) {
  __builtin_amdgcn_global_load_lds(
      (const __attribute__((address_space(1))) unsigned int*)g,
      (__attribute__((address_space(3))) unsigned int*)l, 16, 0, 0);
}

// ---------------- kernel 0: weights -> bf16 head-grouped [k32|v32|q32], zero ctx/S --------
__global__ void k_prep(const float* __restrict__ Wk, const float* __restrict__ bk,
                       const float* __restrict__ Wq, const float* __restrict__ bq,
                       const float* __restrict__ Wv, const float* __restrict__ bv,
                       unsigned short* __restrict__ Wb, float* __restrict__ bb,
                       float* __restrict__ ctx, float* __restrict__ S) {
  int idx = blockIdx.x * 256 + threadIdx.x;
  if (idx < NHEADS * 96 * CCH) {
    int c = idx & (CCH - 1);
    int row = (idx >> 8) % 96;
    int h = idx / (96 * CCH);
    int ch = h * HC;
    float val;
    if (row < HC)          val = Wk[(ch + row) * CCH + c];
    else if (row < 2 * HC) val = Wv[(ch + row - HC) * CCH + c];
    else                   val = Wq[(ch + row - 2 * HC) * CCH + c];
    Wb[idx] = f2bf(val);
  }
  if (idx < NHEADS * 96) {
    int row = idx % 96, h = idx / 96, ch = h * HC;
    float val;
    if (row < HC)          val = bk[ch + row];
    else if (row < 2 * HC) val = bv[ch + row - HC];
    else                   val = bq[ch + row - 2 * HC];
    bb[idx] = val;
  }
  if (idx < NB * NHEADS * HC * HC) ctx[idx] = 0.f;
  if (idx < NB * NHEADS * HC)      S[idx]   = 0.f;
}

// ---------------- kernel 0b: x [n][c][l] f32 -> xT [n][l][c] bf16 ----------------
__global__ __launch_bounds__(256)
void k_transpose(const float* __restrict__ x, unsigned short* __restrict__ xT) {
  __shared__ float tile[64][65];
  int b = blockIdx.x;
  int ct = b & 3;
  int lt = (b >> 2) & 255;
  int n  = b >> 10;
  int c0 = ct * 64, l0 = lt * 64;
  int t = threadIdx.x;
  int li = t & 63, cr = t >> 6;
  const float* xp = x + (size_t)n * CCH * LSP;
#pragma unroll
  for (int i = 0; i < 16; ++i) {
    int ci = cr * 16 + i;
    tile[ci][li] = xp[(size_t)(c0 + ci) * LSP + l0 + li];
  }
  __syncthreads();
  int cp = t & 31, l8 = t >> 5;
  unsigned short* xo = xT + ((size_t)n * LSP + l0) * CCH + c0;
#pragma unroll
  for (int i = 0; i < 8; ++i) {
    int l = l8 * 8 + i;
    unsigned pk = (unsigned)f2bf(tile[2 * cp][l]) | ((unsigned)f2bf(tile[2 * cp + 1][l]) << 16);
    *(unsigned*)&xo[(size_t)l * CCH + 2 * cp] = pk;
  }
}

// ---------------- kernel 1: fused QKV, 1 block/CU, 48x64 wave tiles ----------------
// grid 256: bid = h*32 + (n*4 + q2); 8 h-siblings (same x-slice) share bid%8 -> one XCD.
// Block = 1 head x 4096 px (32 tiles of 128 px). 4 waves = (rh: 48-row half) x (pq: 64-px half).
// rh0 rows 0-47: k(32)+v(0-15), all swapped mfma(x,W) -> lane = 4 contig px.
// rh1 rows 48-95: v(16-31) swapped + q(32) normal -> q softmax fully in-wave, direct stores.
// Per kk: 3 W + 4 x reads -> 12 MFMA (ratio 0.58). Strips double-buffered: ctx MFMA of tile
// t runs at top of iter t+1 (and after the loop), so each tile has exactly 2 barriers.
__global__ __launch_bounds__(256)
void k_fused(const unsigned short* __restrict__ xT,
             const unsigned short* __restrict__ Wb, const float* __restrict__ bb,
             unsigned short* __restrict__ qbuf, float* __restrict__ ctx,
             float* __restrict__ S) {
  __shared__ unsigned short wlds[96 * 256];     // 48 KiB (staged once)
  __shared__ unsigned short xt[128 * 256];      // 64 KiB (single buffer)
  __shared__ unsigned short ekst[2][32][136];   // 17 KiB exp(k) strips, dbuf
  __shared__ unsigned short vst[2][32][136];    // 17 KiB v strips, dbuf

  int bid = (int)blockIdx.x;
  int h = bid >> 5;
  int r5 = bid & 31;
  int n = r5 >> 2, q2 = r5 & 3;
  int l0 = q2 << 12;
  int nh = n * NHEADS + h;
  int tid = threadIdx.x;
  int wid = tid >> 6, lane = tid & 63;
  int r16 = lane & 15, kg = lane >> 4;
  int rh = wid >> 1, pq = wid & 1;

  const unsigned short* xTn = xT + ((size_t)n << 14) * CCH;
  const unsigned short* Wh = Wb + (size_t)h * 96 * CCH;

  // stage 128px x 256ch tile: 64 x 1KiB pieces, 16/wave; dest linear,
  // source chunk-XOR-swizzled (both-sides involution, rule 21)
  auto stage_xt = [&](int tt) {
    int lb = l0 + tt * 128;
#pragma unroll
    for (int i = 0; i < 16; ++i) {
      int p = wid * 16 + i;
      int px = 2 * p + (lane >> 5);
      int cc = lane & 31;
      gload_lds16(xTn + ((size_t)(lb + px) << 8) + ((cc ^ (px & 7)) << 3),
                  xt + p * 512);
    }
  };

  // prologue: W (48 pieces, 12/wave) + first x tile
#pragma unroll
  for (int i = 0; i < 12; ++i) {
    int p = wid * 12 + i;
    int row = 2 * p + (lane >> 5);
    int cc = lane & 31;
    gload_lds16(Wh + ((size_t)row << 8) + ((cc ^ (row & 7)) << 3), wlds + p * 512);
  }
  stage_xt(0);

  // biases: swapped frags keyed by wrow=r16; q (normal) keyed by kg*4+r
  float bw[3];
#pragma unroll
  for (int m = 0; m < 3; ++m) bw[m] = bb[h * 96 + rh * 48 + m * 16 + r16];
  float bq[2][4];
#pragma unroll
  for (int m = 0; m < 2; ++m)
#pragma unroll
    for (int r = 0; r < 4; ++r) bq[m][r] = bb[h * 96 + 64 + m * 16 + kg * 4 + r];

  f32x4 actx = {0.f, 0.f, 0.f, 0.f};   // this wave's ctx quadrant (ckf=rh, cvf=pq)
  float sk0 = 0.f, sk1 = 0.f;

  asm volatile("s_waitcnt vmcnt(0)" ::: "memory");
  __builtin_amdgcn_sched_barrier(0);
  __builtin_amdgcn_s_barrier();
  __builtin_amdgcn_sched_barrier(0);

  const unsigned short* wbase = wlds + (rh * 48 + r16) * 256;
  const unsigned short* xbase = xt + (pq * 64 + r16) * 256;

  for (int t = 0; t < NT; ++t) {
    int sb = t & 1, pb = sb ^ 1;
    // ---- ctx MFMA on previous tile's strips (pipelined one tile behind) ----
    if (t) {
#pragma unroll
      for (int ks = 0; ks < 4; ++ks) {
        short8 a = *(const short8*)&ekst[pb][rh * 16 + r16][ks * 32 + kg * 8];
        short8 b = *(const short8*)&vst[pb][pq * 16 + r16][ks * 32 + kg * 8];
        actx = __builtin_amdgcn_mfma_f32_16x16x32_bf16(a, b, actx, 0, 0, 0);
      }
    }
    // ---- K-loop: 96 rows x 64 px, 7 reads -> 12 MFMA per kk ----
    f32x4 acc[3][4];
#pragma unroll
    for (int m = 0; m < 3; ++m)
#pragma unroll
      for (int nf = 0; nf < 4; ++nf) acc[m][nf] = (f32x4){0.f, 0.f, 0.f, 0.f};
#pragma unroll
    for (int kk = 0; kk < 8; ++kk) {
      int co = (((kk * 4 + kg) ^ (r16 & 7)) << 3);
      short8 wf0 = *(const short8*)&wbase[co];
      short8 wf1 = *(const short8*)&wbase[4096 + co];
      short8 wf2 = *(const short8*)&wbase[8192 + co];
      short8 xf[4];
#pragma unroll
      for (int nf = 0; nf < 4; ++nf) xf[nf] = *(const short8*)&xbase[nf * 4096 + co];
      if (rh == 0) {
#pragma unroll
        for (int nf = 0; nf < 4; ++nf) {
          acc[0][nf] = __builtin_amdgcn_mfma_f32_16x16x32_bf16(xf[nf], wf0, acc[0][nf], 0, 0, 0);
          acc[1][nf] = __builtin_amdgcn_mfma_f32_16x16x32_bf16(xf[nf], wf1, acc[1][nf], 0, 0, 0);
          acc[2][nf] = __builtin_amdgcn_mfma_f32_16x16x32_bf16(xf[nf], wf2, acc[2][nf], 0, 0, 0);
        }
      } else {
#pragma unroll
        for (int nf = 0; nf < 4; ++nf) {
          acc[0][nf] = __builtin_amdgcn_mfma_f32_16x16x32_bf16(xf[nf], wf0, acc[0][nf], 0, 0, 0);
          acc[1][nf] = __builtin_amdgcn_mfma_f32_16x16x32_bf16(wf1, xf[nf], acc[1][nf], 0, 0, 0);
          acc[2][nf] = __builtin_amdgcn_mfma_f32_16x16x32_bf16(wf2, xf[nf], acc[2][nf], 0, 0, 0);
        }
      }
    }
    __builtin_amdgcn_s_barrier();          // barrier1: all waves done reading xt
    if (t + 1 < NT) stage_xt(t + 1);       // DMA flies under the epilogue

    // ---- epilogue (wave-local) ----
    if (rh == 0) {
#pragma unroll
      for (int nf = 0; nf < 4; ++nf) {
        int col = pq * 64 + nf * 16 + kg * 4;
#pragma unroll
        for (int m = 0; m < 2; ++m) {       // k rows -> exp strips + S
          float e0 = __expf(acc[m][nf][0] + bw[m]);
          float e1 = __expf(acc[m][nf][1] + bw[m]);
          float e2 = __expf(acc[m][nf][2] + bw[m]);
          float e3 = __expf(acc[m][nf][3] + bw[m]);
          if (m == 0) sk0 += e0 + e1 + e2 + e3; else sk1 += e0 + e1 + e2 + e3;
          uint2 u = {cvt_pk_bf16(e0, e1), cvt_pk_bf16(e2, e3)};
          *(uint2*)&ekst[sb][m * 16 + r16][col] = u;
        }
        {                                    // v rows 0-15
          float v0 = acc[2][nf][0] + bw[2], v1 = acc[2][nf][1] + bw[2];
          float v2 = acc[2][nf][2] + bw[2], v3 = acc[2][nf][3] + bw[2];
          uint2 u = {cvt_pk_bf16(v0, v1), cvt_pk_bf16(v2, v3)};
          *(uint2*)&vst[sb][r16][col] = u;
        }
      }
    } else {
#pragma unroll
      for (int nf = 0; nf < 4; ++nf) {
        int col = pq * 64 + nf * 16 + kg * 4;
        {                                    // v rows 16-31
          float v0 = acc[0][nf][0] + bw[0], v1 = acc[0][nf][1] + bw[0];
          float v2 = acc[0][nf][2] + bw[0], v3 = acc[0][nf][3] + bw[0];
          uint2 u = {cvt_pk_bf16(v0, v1), cvt_pk_bf16(v2, v3)};
          *(uint2*)&vst[sb][16 + r16][col] = u;
        }
        // q: softmax over 32 ck, wholly in-wave (8 in-lane + shfl 16,32)
        float ea[4], eb[4];
        float s = 0.f;
#pragma unroll
        for (int r = 0; r < 4; ++r) {
          ea[r] = __expf(acc[1][nf][r] + bq[0][r]);
          eb[r] = __expf(acc[2][nf][r] + bq[1][r]);
          s += ea[r] + eb[r];
        }
        s += __shfl_xor(s, 16);
        s += __shfl_xor(s, 32);
        float inv = 1.f / s;
        int l = l0 + t * 128 + pq * 64 + nf * 16 + r16;
        unsigned short* qb = qbuf + (((size_t)nh * LSP + l) << 5);
        uint2 u0 = {cvt_pk_bf16(ea[0] * inv, ea[1] * inv), cvt_pk_bf16(ea[2] * inv, ea[3] * inv)};
        uint2 u1 = {cvt_pk_bf16(eb[0] * inv, eb[1] * inv), cvt_pk_bf16(eb[2] * inv, eb[3] * inv)};
        *(uint2*)&qb[kg * 4]      = u0;
        *(uint2*)&qb[16 + kg * 4] = u1;
      }
    }
    // barrier2: strips visible, xt staged (per-wave counted vmcnt; q-stores linger)
    asm volatile("s_waitcnt lgkmcnt(0)" ::: "memory");
    __builtin_amdgcn_sched_barrier(0);
    if (rh == 0) { asm volatile("s_waitcnt vmcnt(0)" ::: "memory"); }
    else         { asm volatile("s_waitcnt vmcnt(8)" ::: "memory"); }
    __builtin_amdgcn_sched_barrier(0);
    __builtin_amdgcn_s_barrier();
    __builtin_amdgcn_sched_barrier(0);
  }

  // final ctx on last tile's strips
#pragma unroll
  for (int ks = 0; ks < 4; ++ks) {
    short8 a = *(const short8*)&ekst[(NT - 1) & 1][rh * 16 + r16][ks * 32 + kg * 8];
    short8 b = *(const short8*)&vst[(NT - 1) & 1][pq * 16 + r16][ks * 32 + kg * 8];
    actx = __builtin_amdgcn_mfma_f32_16x16x32_bf16(a, b, actx, 0, 0, 0);
  }
  // flush: ctx quadrant + S rows (rh0 waves hold all k rows; both pq waves add)
  float* cp = ctx + ((size_t)nh << 10);
#pragma unroll
  for (int r = 0; r < 4; ++r)
    atomicAdd(&cp[(rh * 16 + kg * 4 + r) * HC + pq * 16 + r16], actx[r]);
  if (rh == 0) {
    float s0 = sk0, s1 = sk1;
    s0 += __shfl_xor(s0, 16); s0 += __shfl_xor(s0, 32);
    s1 += __shfl_xor(s1, 16); s1 += __shfl_xor(s1, 32);
    if (kg == 0) {
      atomicAdd(&S[nh * HC + r16], s0);
      atomicAdd(&S[nh * HC + 16 + r16], s1);
    }
  }
}

// ---------------- kernel 2: ctx/S, transpose, -> bf16 ----------------
__global__ void k_norm(const float* __restrict__ ctx, const float* __restrict__ S,
                       unsigned short* __restrict__ ctxT) {
  int idx = blockIdx.x * 256 + threadIdx.x;  // 65536 = [n][h][ck][cv]
  int cv = idx & 31, ck = (idx >> 5) & 31, nh = idx >> 10;
  float v = ctx[idx] / S[(nh << 5) + ck];
  ctxT[(nh << 10) + (cv << 5) + ck] = f2bf(v);
}

// ---------------- kernel 3: att = ctxT (32x32) x q_soft (32 x L) + residual ----------------
__global__ __launch_bounds__(256)
void k_att(const float* __restrict__ x, const unsigned short* __restrict__ qbuf,
           const unsigned short* __restrict__ ctxT, float* __restrict__ out) {
  int b = blockIdx.x;
  int lc = b & 63;
  int nh = b >> 6;
  int h = nh & 7, n = nh >> 3;
  int tid = threadIdx.x, wid = tid >> 6, lane = tid & 63;
  int r16 = lane & 15, kg = lane >> 4;
  int lw = lc * 256 + wid * 64;

  const unsigned short* cp = ctxT + ((size_t)nh << 10);
  short8 a0 = *(const short8*)&cp[(r16 << 5) + kg * 8];          // A[cv][ck], cv 0-15
  short8 a1 = *(const short8*)&cp[((16 + r16) << 5) + kg * 8];   // cv 16-31
  const unsigned short* qb = qbuf + (((size_t)nh * LSP) << 5);
  const float* xp = x   + ((size_t)n * CCH + (size_t)h * HC) * LSP;
  float*       op = out + ((size_t)n * CCH + (size_t)h * HC) * LSP;

#pragma unroll
  for (int t = 0; t < 4; ++t) {
    int l = lw + t * 16;
    short8 bf = *(const short8*)&qb[((size_t)(l + r16) << 5) + kg * 8];  // softmaxed q [l][ck]
    f32x4 d0 = {0, 0, 0, 0}, d1 = {0, 0, 0, 0};
    d0 = __builtin_amdgcn_mfma_f32_16x16x32_bf16(a0, bf, d0, 0, 0, 0);
    d1 = __builtin_amdgcn_mfma_f32_16x16x32_bf16(a1, bf, d1, 0, 0, 0);
#pragma unroll
    for (int r = 0; r < 4; ++r) {
      int cv = kg * 4 + r;
      int li = l + r16;
      op[(size_t)cv * LSP + li]        = d0[r] + xp[(size_t)cv * LSP + li];
      op[(size_t)(cv + 16) * LSP + li] = d1[r] + xp[(size_t)(cv + 16) * LSP + li];
    }
  }
}

extern "C" void kernel_launch(void* const* d_in, const int* in_sizes, int n_in,
                              void* d_out, int out_size, void* d_ws, size_t ws_size,
                              hipStream_t stream) {
  (void)in_sizes; (void)n_in; (void)out_size; (void)ws_size;
  const float* x  = (const float*)d_in[0];
  const float* Wk = (const float*)d_in[1];
  const float* bk = (const float*)d_in[2];
  const float* Wq = (const float*)d_in[3];
  const float* bq = (const float*)d_in[4];
  const float* Wv = (const float*)d_in[5];
  const float* bv = (const float*)d_in[6];
  float* out = (float*)d_out;

  char* ws = (char*)d_ws;
  unsigned short* Wb   = (unsigned short*)(ws + 0);          //   393216
  float*          bbp  = (float*)(ws + 393216);              //     3072
  float*          ctx  = (float*)(ws + 396288);              //   262144
  unsigned short* ctxT = (unsigned short*)(ws + 658432);     //   131072
  float*          S    = (float*)(ws + 789504);              //     8192
  unsigned short* qbuf = (unsigned short*)(ws + 797696);     // 67108864
  unsigned short* xT   = (unsigned short*)(ws + 67906560);   // 67108864 -> 135015424 total

  k_prep<<<768, 256, 0, stream>>>(Wk, bk, Wq, bq, Wv, bv, Wb, bbp, ctx, S);
  k_transpose<<<NB * 256 * 4, 256, 0, stream>>>(x, xT);
  k_fused<<<256, 256, 0, stream>>>(xT, Wb, bbp, qbuf, ctx, S);
  k_norm<<<256, 256, 0, stream>>>(ctx, S, ctxT);
  k_att<<<NB * NHEADS * 64, 256, 0, stream>>>(x, qbuf, ctxT, out);
}

// Round 13
// 209.303 us; speedup vs baseline: 1.4794x; 1.0394x over previous
//
#include <hip/hip_runtime.h>

// EfficientAttention: N=8, C=256, H=W=128 (L=16384), HEADS=8, hc=32
// out = x + att,  att[n,h,cv,l] = sum_ck (ctx[ck,cv]/S[ck]) * softmax_ck(q)[ck,l]
// ctx[ck,cv] = sum_l exp(k[ck,l]) * v[cv,l],  S[ck] = sum_l exp(k[ck,l])
//
// R13: R12 structure (LDS-streamed operands, strip-dbuf ctx pipeline, 2 barriers
// per tile) but 8 waves/block (512 thr) -> 2 waves/SIMD so dependency stalls
// co-schedule. Wave tile 48x32 (rh half x px quarter). R12 was 1 wave/SIMD and
// ran 3x its port floor purely on exposed latency.

typedef __attribute__((ext_vector_type(8))) short short8;
typedef __attribute__((ext_vector_type(4))) float f32x4;

#define NB     8
#define CCH    256
#define LSP    16384
#define NHEADS 8
#define HC     32
#define NT     32     // 128-px tiles per block (4096-px quarter-L)

__device__ __forceinline__ unsigned short f2bf(float f) {
  union { float f; unsigned u; } v; v.f = f;
  unsigned r = v.u + 0x7fffu + ((v.u >> 16) & 1u);   // RNE
  return (unsigned short)(r >> 16);
}
__device__ __forceinline__ unsigned cvt_pk_bf16(float lo, float hi) {
  unsigned r;
  asm("v_cvt_pk_bf16_f32 %0, %1, %2" : "=v"(r) : "v"(lo), "v"(hi));
  return r;
}
__device__ __forceinline__ void gload_lds16(const unsigned short* g, unsigned short* l) {
  __builtin_amdgcn_global_load_lds(
      (const __attribute__((address_space(1))) unsigned int*)g,
      (__attribute__((address_space(3))) unsigned int*)l, 16, 0, 0);
}

// ---------------- kernel 0: weights -> bf16 head-grouped [k32|v32|q32], zero ctx/S --------
__global__ void k_prep(const float* __restrict__ Wk, const float* __restrict__ bk,
                       const float* __restrict__ Wq, const float* __restrict__ bq,
                       const float* __restrict__ Wv, const float* __restrict__ bv,
                       unsigned short* __restrict__ Wb, float* __restrict__ bb,
                       float* __restrict__ ctx, float* __restrict__ S) {
  int idx = blockIdx.x * 256 + threadIdx.x;
  if (idx < NHEADS * 96 * CCH) {
    int c = idx & (CCH - 1);
    int row = (idx >> 8) % 96;
    int h = idx / (96 * CCH);
    int ch = h * HC;
    float val;
    if (row < HC)          val = Wk[(ch + row) * CCH + c];
    else if (row < 2 * HC) val = Wv[(ch + row - HC) * CCH + c];
    else                   val = Wq[(ch + row - 2 * HC) * CCH + c];
    Wb[idx] = f2bf(val);
  }
  if (idx < NHEADS * 96) {
    int row = idx % 96, h = idx / 96, ch = h * HC;
    float val;
    if (row < HC)          val = bk[ch + row];
    else if (row < 2 * HC) val = bv[ch + row - HC];
    else                   val = bq[ch + row - 2 * HC];
    bb[idx] = val;
  }
  if (idx < NB * NHEADS * HC * HC) ctx[idx] = 0.f;
  if (idx < NB * NHEADS * HC)      S[idx]   = 0.f;
}

// ---------------- kernel 0b: x [n][c][l] f32 -> xT [n][l][c] bf16 ----------------
__global__ __launch_bounds__(256)
void k_transpose(const float* __restrict__ x, unsigned short* __restrict__ xT) {
  __shared__ float tile[64][65];
  int b = blockIdx.x;
  int ct = b & 3;
  int lt = (b >> 2) & 255;
  int n  = b >> 10;
  int c0 = ct * 64, l0 = lt * 64;
  int t = threadIdx.x;
  int li = t & 63, cr = t >> 6;
  const float* xp = x + (size_t)n * CCH * LSP;
#pragma unroll
  for (int i = 0; i < 16; ++i) {
    int ci = cr * 16 + i;
    tile[ci][li] = xp[(size_t)(c0 + ci) * LSP + l0 + li];
  }
  __syncthreads();
  int cp = t & 31, l8 = t >> 5;
  unsigned short* xo = xT + ((size_t)n * LSP + l0) * CCH + c0;
#pragma unroll
  for (int i = 0; i < 8; ++i) {
    int l = l8 * 8 + i;
    unsigned pk = (unsigned)f2bf(tile[2 * cp][l]) | ((unsigned)f2bf(tile[2 * cp + 1][l]) << 16);
    *(unsigned*)&xo[(size_t)l * CCH + 2 * cp] = pk;
  }
}

// ---------------- kernel 1: fused QKV, 8 waves (2/SIMD), 48x32 wave tiles ----------------
// grid 256: bid = h*32 + (n*4 + q2); 8 h-siblings (same x-slice) share bid%8 -> one XCD.
// Block = 1 head x 4096 px (32 tiles of 128 px). 8 waves = rh{0,1} x pq{0..3}.
// rh0 rows 0-47: k(32)+v(0-15), swapped mfma(x,W); rh1 rows 48-95: v(16-31) swapped
// + q(32) normal (softmax fully in-wave). Strips double-buffered; ctx MFMA of tile t
// runs at top of iter t+1 (K split across pq>>1). 2 barriers/tile, per-role vmcnt.
__global__ __launch_bounds__(512)
void k_fused(const unsigned short* __restrict__ xT,
             const unsigned short* __restrict__ Wb, const float* __restrict__ bb,
             unsigned short* __restrict__ qbuf, float* __restrict__ ctx,
             float* __restrict__ S) {
  __shared__ unsigned short wlds[96 * 256];     // 48 KiB (staged once)
  __shared__ unsigned short xt[128 * 256];      // 64 KiB (single buffer)
  __shared__ unsigned short ekst[2][32][136];   // 17 KiB exp(k) strips, dbuf
  __shared__ unsigned short vst[2][32][136];    // 17 KiB v strips, dbuf

  int bid = (int)blockIdx.x;
  int h = bid >> 5;
  int r5 = bid & 31;
  int n = r5 >> 2, q2 = r5 & 3;
  int l0 = q2 << 12;
  int nh = n * NHEADS + h;
  int tid = threadIdx.x;
  int wid = tid >> 6, lane = tid & 63;
  int r16 = lane & 15, kg = lane >> 4;
  int rh = wid >> 2;          // row half (48 rows)
  int pq = wid & 3;           // px quarter (32 px)

  const unsigned short* xTn = xT + ((size_t)n << 14) * CCH;
  const unsigned short* Wh = Wb + (size_t)h * 96 * CCH;

  // stage 128px x 256ch tile: 64 x 1KiB pieces, 8/wave; dest linear,
  // source chunk-XOR-swizzled (both-sides involution, rule 21)
  auto stage_xt = [&](int tt) {
    int lb = l0 + tt * 128;
#pragma unroll
    for (int i = 0; i < 8; ++i) {
      int p = wid * 8 + i;
      int px = 2 * p + (lane >> 5);
      int cc = lane & 31;
      gload_lds16(xTn + ((size_t)(lb + px) << 8) + ((cc ^ (px & 7)) << 3),
                  xt + p * 512);
    }
  };

  // prologue: W (48 pieces, 6/wave) + first x tile
#pragma unroll
  for (int i = 0; i < 6; ++i) {
    int p = wid * 6 + i;
    int row = 2 * p + (lane >> 5);
    int cc = lane & 31;
    gload_lds16(Wh + ((size_t)row << 8) + ((cc ^ (row & 7)) << 3), wlds + p * 512);
  }
  stage_xt(0);

  // biases: swapped frags keyed by wrow=r16; q (normal) keyed by kg*4+r
  float bw[3];
#pragma unroll
  for (int m = 0; m < 3; ++m) bw[m] = bb[h * 96 + rh * 48 + m * 16 + r16];
  float bq[2][4];
#pragma unroll
  for (int m = 0; m < 2; ++m)
#pragma unroll
    for (int r = 0; r < 4; ++r) bq[m][r] = bb[h * 96 + 64 + m * 16 + kg * 4 + r];

  f32x4 actx = {0.f, 0.f, 0.f, 0.f};   // quadrant (ckf=rh, cvf=pq&1), K-half pq>>1
  float sk0 = 0.f, sk1 = 0.f;

  asm volatile("s_waitcnt vmcnt(0)" ::: "memory");
  __builtin_amdgcn_sched_barrier(0);
  __builtin_amdgcn_s_barrier();
  __builtin_amdgcn_sched_barrier(0);

  const unsigned short* wbase = wlds + (rh * 48 + r16) * 256;
  const unsigned short* xbase = xt + (pq * 32 + r16) * 256;
  int kh = pq >> 1, cvf = pq & 1;

  for (int t = 0; t < NT; ++t) {
    int sb = t & 1, pb = sb ^ 1;
    // ---- ctx MFMA on previous tile's strips (pipelined one tile behind) ----
    if (t) {
#pragma unroll
      for (int ks = 0; ks < 2; ++ks) {
        int col = kh * 64 + ks * 32 + kg * 8;
        short8 a = *(const short8*)&ekst[pb][rh * 16 + r16][col];
        short8 b = *(const short8*)&vst[pb][cvf * 16 + r16][col];
        actx = __builtin_amdgcn_mfma_f32_16x16x32_bf16(a, b, actx, 0, 0, 0);
      }
    }
    // ---- K-loop: 48 rows x 32 px, 5 reads -> 6 MFMA per kk ----
    f32x4 acc[3][2];
#pragma unroll
    for (int m = 0; m < 3; ++m) { acc[m][0] = (f32x4){0,0,0,0}; acc[m][1] = (f32x4){0,0,0,0}; }
#pragma unroll
    for (int kk = 0; kk < 8; ++kk) {
      int co = (((kk * 4 + kg) ^ (r16 & 7)) << 3);
      short8 wf0 = *(const short8*)&wbase[co];
      short8 wf1 = *(const short8*)&wbase[4096 + co];
      short8 wf2 = *(const short8*)&wbase[8192 + co];
      short8 xf0 = *(const short8*)&xbase[co];
      short8 xf1 = *(const short8*)&xbase[4096 + co];
      if (rh == 0) {
        acc[0][0] = __builtin_amdgcn_mfma_f32_16x16x32_bf16(xf0, wf0, acc[0][0], 0, 0, 0);
        acc[0][1] = __builtin_amdgcn_mfma_f32_16x16x32_bf16(xf1, wf0, acc[0][1], 0, 0, 0);
        acc[1][0] = __builtin_amdgcn_mfma_f32_16x16x32_bf16(xf0, wf1, acc[1][0], 0, 0, 0);
        acc[1][1] = __builtin_amdgcn_mfma_f32_16x16x32_bf16(xf1, wf1, acc[1][1], 0, 0, 0);
        acc[2][0] = __builtin_amdgcn_mfma_f32_16x16x32_bf16(xf0, wf2, acc[2][0], 0, 0, 0);
        acc[2][1] = __builtin_amdgcn_mfma_f32_16x16x32_bf16(xf1, wf2, acc[2][1], 0, 0, 0);
      } else {
        acc[0][0] = __builtin_amdgcn_mfma_f32_16x16x32_bf16(xf0, wf0, acc[0][0], 0, 0, 0);
        acc[0][1] = __builtin_amdgcn_mfma_f32_16x16x32_bf16(xf1, wf0, acc[0][1], 0, 0, 0);
        acc[1][0] = __builtin_amdgcn_mfma_f32_16x16x32_bf16(wf1, xf0, acc[1][0], 0, 0, 0);
        acc[1][1] = __builtin_amdgcn_mfma_f32_16x16x32_bf16(wf1, xf1, acc[1][1], 0, 0, 0);
        acc[2][0] = __builtin_amdgcn_mfma_f32_16x16x32_bf16(wf2, xf0, acc[2][0], 0, 0, 0);
        acc[2][1] = __builtin_amdgcn_mfma_f32_16x16x32_bf16(wf2, xf1, acc[2][1], 0, 0, 0);
      }
    }
    __builtin_amdgcn_s_barrier();          // barrier1: all waves done reading xt
    if (t + 1 < NT) stage_xt(t + 1);       // DMA flies under the epilogue

    // ---- epilogue (wave-local) ----
    if (rh == 0) {
#pragma unroll
      for (int nf = 0; nf < 2; ++nf) {
        int col = pq * 32 + nf * 16 + kg * 4;
#pragma unroll
        for (int m = 0; m < 2; ++m) {       // k rows -> exp strips + S
          float e0 = __expf(acc[m][nf][0] + bw[m]);
          float e1 = __expf(acc[m][nf][1] + bw[m]);
          float e2 = __expf(acc[m][nf][2] + bw[m]);
          float e3 = __expf(acc[m][nf][3] + bw[m]);
          if (m == 0) sk0 += e0 + e1 + e2 + e3; else sk1 += e0 + e1 + e2 + e3;
          uint2 u = {cvt_pk_bf16(e0, e1), cvt_pk_bf16(e2, e3)};
          *(uint2*)&ekst[sb][m * 16 + r16][col] = u;
        }
        {                                    // v rows 0-15
          float v0 = acc[2][nf][0] + bw[2], v1 = acc[2][nf][1] + bw[2];
          float v2 = acc[2][nf][2] + bw[2], v3 = acc[2][nf][3] + bw[2];
          uint2 u = {cvt_pk_bf16(v0, v1), cvt_pk_bf16(v2, v3)};
          *(uint2*)&vst[sb][r16][col] = u;
        }
      }
    } else {
#pragma unroll
      for (int nf = 0; nf < 2; ++nf) {
        int col = pq * 32 + nf * 16 + kg * 4;
        {                                    // v rows 16-31
          float v0 = acc[0][nf][0] + bw[0], v1 = acc[0][nf][1] + bw[0];
          float v2 = acc[0][nf][2] + bw[0], v3 = acc[0][nf][3] + bw[0];
          uint2 u = {cvt_pk_bf16(v0, v1), cvt_pk_bf16(v2, v3)};
          *(uint2*)&vst[sb][16 + r16][col] = u;
        }
        // q: softmax over 32 ck, wholly in-wave (8 in-lane + shfl 16,32)
        float ea[4], eb[4];
        float s = 0.f;
#pragma unroll
        for (int r = 0; r < 4; ++r) {
          ea[r] = __expf(acc[1][nf][r] + bq[0][r]);
          eb[r] = __expf(acc[2][nf][r] + bq[1][r]);
          s += ea[r] + eb[r];
        }
        s += __shfl_xor(s, 16);
        s += __shfl_xor(s, 32);
        float inv = 1.f / s;
        int l = l0 + t * 128 + pq * 32 + nf * 16 + r16;
        unsigned short* qb = qbuf + (((size_t)nh * LSP + l) << 5);
        uint2 u0 = {cvt_pk_bf16(ea[0] * inv, ea[1] * inv), cvt_pk_bf16(ea[2] * inv, ea[3] * inv)};
        uint2 u1 = {cvt_pk_bf16(eb[0] * inv, eb[1] * inv), cvt_pk_bf16(eb[2] * inv, eb[3] * inv)};
        *(uint2*)&qb[kg * 4]      = u0;
        *(uint2*)&qb[16 + kg * 4] = u1;
      }
    }
    // barrier2: strips visible, xt staged (per-role counted vmcnt; q-stores linger)
    asm volatile("s_waitcnt lgkmcnt(0)" ::: "memory");
    __builtin_amdgcn_sched_barrier(0);
    if (rh == 0) { asm volatile("s_waitcnt vmcnt(0)" ::: "memory"); }
    else         { asm volatile("s_waitcnt vmcnt(4)" ::: "memory"); }
    __builtin_amdgcn_sched_barrier(0);
    __builtin_amdgcn_s_barrier();
    __builtin_amdgcn_sched_barrier(0);
  }

  // final ctx on last tile's strips
#pragma unroll
  for (int ks = 0; ks < 2; ++ks) {
    int col = kh * 64 + ks * 32 + kg * 8;
    short8 a = *(const short8*)&ekst[(NT - 1) & 1][rh * 16 + r16][col];
    short8 b = *(const short8*)&vst[(NT - 1) & 1][cvf * 16 + r16][col];
    actx = __builtin_amdgcn_mfma_f32_16x16x32_bf16(a, b, actx, 0, 0, 0);
  }
  // flush: ctx quadrant + S rows (rh0 waves hold all k rows; 4 pq waves add)
  float* cp = ctx + ((size_t)nh << 10);
#pragma unroll
  for (int r = 0; r < 4; ++r)
    atomicAdd(&cp[(rh * 16 + kg * 4 + r) * HC + cvf * 16 + r16], actx[r]);
  if (rh == 0) {
    float s0 = sk0, s1 = sk1;
    s0 += __shfl_xor(s0, 16); s0 += __shfl_xor(s0, 32);
    s1 += __shfl_xor(s1, 16); s1 += __shfl_xor(s1, 32);
    if (kg == 0) {
      atomicAdd(&S[nh * HC + r16], s0);
      atomicAdd(&S[nh * HC + 16 + r16], s1);
    }
  }
}

// ---------------- kernel 2: ctx/S, transpose, -> bf16 ----------------
__global__ void k_norm(const float* __restrict__ ctx, const float* __restrict__ S,
                       unsigned short* __restrict__ ctxT) {
  int idx = blockIdx.x * 256 + threadIdx.x;  // 65536 = [n][h][ck][cv]
  int cv = idx & 31, ck = (idx >> 5) & 31, nh = idx >> 10;
  float v = ctx[idx] / S[(nh << 5) + ck];
  ctxT[(nh << 10) + (cv << 5) + ck] = f2bf(v);
}

// ---------------- kernel 3: att = ctxT (32x32) x q_soft (32 x L) + residual ----------------
__global__ __launch_bounds__(256)
void k_att(const float* __restrict__ x, const unsigned short* __restrict__ qbuf,
           const unsigned short* __restrict__ ctxT, float* __restrict__ out) {
  int b = blockIdx.x;
  int lc = b & 63;
  int nh = b >> 6;
  int h = nh & 7, n = nh >> 3;
  int tid = threadIdx.x, wid = tid >> 6, lane = tid & 63;
  int r16 = lane & 15, kg = lane >> 4;
  int lw = lc * 256 + wid * 64;

  const unsigned short* cp = ctxT + ((size_t)nh << 10);
  short8 a0 = *(const short8*)&cp[(r16 << 5) + kg * 8];          // A[cv][ck], cv 0-15
  short8 a1 = *(const short8*)&cp[((16 + r16) << 5) + kg * 8];   // cv 16-31
  const unsigned short* qb = qbuf + (((size_t)nh * LSP) << 5);
  const float* xp = x   + ((size_t)n * CCH + (size_t)h * HC) * LSP;
  float*       op = out + ((size_t)n * CCH + (size_t)h * HC) * LSP;

#pragma unroll
  for (int t = 0; t < 4; ++t) {
    int l = lw + t * 16;
    short8 bf = *(const short8*)&qb[((size_t)(l + r16) << 5) + kg * 8];  // softmaxed q [l][ck]
    f32x4 d0 = {0, 0, 0, 0}, d1 = {0, 0, 0, 0};
    d0 = __builtin_amdgcn_mfma_f32_16x16x32_bf16(a0, bf, d0, 0, 0, 0);
    d1 = __builtin_amdgcn_mfma_f32_16x16x32_bf16(a1, bf, d1, 0, 0, 0);
#pragma unroll
    for (int r = 0; r < 4; ++r) {
      int cv = kg * 4 + r;
      int li = l + r16;
      op[(size_t)cv * LSP + li]        = d0[r] + xp[(size_t)cv * LSP + li];
      op[(size_t)(cv + 16) * LSP + li] = d1[r] + xp[(size_t)(cv + 16) * LSP + li];
    }
  }
}

extern "C" void kernel_launch(void* const* d_in, const int* in_sizes, int n_in,
                              void* d_out, int out_size, void* d_ws, size_t ws_size,
                              hipStream_t stream) {
  (void)in_sizes; (void)n_in; (void)out_size; (void)ws_size;
  const float* x  = (const float*)d_in[0];
  const float* Wk = (const float*)d_in[1];
  const float* bk = (const float*)d_in[2];
  const float* Wq = (const float*)d_in[3];
  const float* bq = (const float*)d_in[4];
  const float* Wv = (const float*)d_in[5];
  const float* bv = (const float*)d_in[6];
  float* out = (float*)d_out;

  char* ws = (char*)d_ws;
  unsigned short* Wb   = (unsigned short*)(ws + 0);          //   393216
  float*          bbp  = (float*)(ws + 393216);              //     3072
  float*          ctx  = (float*)(ws + 396288);              //   262144
  unsigned short* ctxT = (unsigned short*)(ws + 658432);     //   131072
  float*          S    = (float*)(ws + 789504);              //     8192
  unsigned short* qbuf = (unsigned short*)(ws + 797696);     // 67108864
  unsigned short* xT   = (unsigned short*)(ws + 67906560);   // 67108864 -> 135015424 total

  k_prep<<<768, 256, 0, stream>>>(Wk, bk, Wq, bq, Wv, bv, Wb, bbp, ctx, S);
  k_transpose<<<NB * 256 * 4, 256, 0, stream>>>(x, xT);
  k_fused<<<256, 512, 0, stream>>>(xT, Wb, bbp, qbuf, ctx, S);
  k_norm<<<256, 256, 0, stream>>>(ctx, S, ctxT);
  k_att<<<NB * NHEADS * 64, 256, 0, stream>>>(x, qbuf, ctxT, out);
}

// Round 14
// 193.864 us; speedup vs baseline: 1.5972x; 1.0796x over previous
//
#include <hip/hip_runtime.h>

// EfficientAttention: N=8, C=256, H=W=128 (L=16384), HEADS=8, hc=32
// out = x + att,  att[n,h,cv,l] = sum_ck (ctx[ck,cv]/S[ck]) * softmax_ck(q)[ck,l]
// ctx[ck,cv] = sum_l exp(k[ck,l]) * v[cv,l],  S[ck] = sum_l exp(k[ck,l])
//
// R14: staging GEMM in fp8 e4m3 (frag = 8B/lane -> LDS traffic halved; W-LDS 24KB,
// xt 32KB/tile enabling a real double-buffer with counted vmcnt). W pre-scaled x64
// (e4m3 normal range); epilogue multiplies acc by 1/64. Downstream (exp-k strips,
// ctx MFMA, q softmax, k_att) stays bf16/f32.

typedef __attribute__((ext_vector_type(8))) short short8;
typedef __attribute__((ext_vector_type(4))) float f32x4;
typedef long long ll;

#define NB     8
#define CCH    256
#define LSP    16384
#define NHEADS 8
#define HC     32
#define NT     32     // 128-px tiles per block (4096-px quarter-L)
#define WSC    0.015625f   // 1/64: undo W pre-scale

__device__ __forceinline__ unsigned short f2bf(float f) {
  union { float f; unsigned u; } v; v.f = f;
  unsigned r = v.u + 0x7fffu + ((v.u >> 16) & 1u);   // RNE
  return (unsigned short)(r >> 16);
}
__device__ __forceinline__ unsigned cvt_pk_bf16(float lo, float hi) {
  unsigned r;
  asm("v_cvt_pk_bf16_f32 %0, %1, %2" : "=v"(r) : "v"(lo), "v"(hi));
  return r;
}
// float -> fp8 e4m3fn (RNE). Values here are < 16, so no overflow concerns.
__device__ __forceinline__ unsigned char f2fp8(float f) {
  union { float f; unsigned u; } v; v.f = f;
  unsigned s = (v.u >> 24) & 0x80u;
  unsigned x = v.u & 0x7FFFFFFFu;
  if (x < 0x3C800000u) {                       // |f| < 2^-6 -> subnormal (units 2^-9)
    float a = fabsf(f);
    int q = (int)rintf(a * 512.f);             // 0..8 (8 rolls into first normal)
    return (unsigned char)(s | (unsigned)q);
  }
  unsigned r = x + 0xFFFFFu + ((x >> 20) & 1u);   // RNE into 3-bit mantissa
  unsigned e = r >> 23;
  unsigned m = (r >> 20) & 7u;
  int fe = (int)e - 120;                       // e - 127 + 7
  if (fe > 15 || (fe == 15 && m == 7)) return (unsigned char)(s | 0x7Eu);
  return (unsigned char)(s | ((unsigned)fe << 3) | m);
}
__device__ __forceinline__ void gload_lds16(const unsigned char* g, unsigned char* l) {
  __builtin_amdgcn_global_load_lds(
      (const __attribute__((address_space(1))) unsigned int*)g,
      (__attribute__((address_space(3))) unsigned int*)l, 16, 0, 0);
}

// ---------------- kernel 0: weights -> fp8 (x64 pre-scale) head-grouped [k32|v32|q32] ------
__global__ void k_prep(const float* __restrict__ Wk, const float* __restrict__ bk,
                       const float* __restrict__ Wq, const float* __restrict__ bq,
                       const float* __restrict__ Wv, const float* __restrict__ bv,
                       unsigned char* __restrict__ Wb, float* __restrict__ bb,
                       float* __restrict__ ctx, float* __restrict__ S) {
  int idx = blockIdx.x * 256 + threadIdx.x;
  if (idx < NHEADS * 96 * CCH) {
    int c = idx & (CCH - 1);
    int row = (idx >> 8) % 96;
    int h = idx / (96 * CCH);
    int ch = h * HC;
    float val;
    if (row < HC)          val = Wk[(ch + row) * CCH + c];
    else if (row < 2 * HC) val = Wv[(ch + row - HC) * CCH + c];
    else                   val = Wq[(ch + row - 2 * HC) * CCH + c];
    Wb[idx] = f2fp8(val * 64.f);
  }
  if (idx < NHEADS * 96) {
    int row = idx % 96, h = idx / 96, ch = h * HC;
    float val;
    if (row < HC)          val = bk[ch + row];
    else if (row < 2 * HC) val = bv[ch + row - HC];
    else                   val = bq[ch + row - 2 * HC];
    bb[idx] = val;
  }
  if (idx < NB * NHEADS * HC * HC) ctx[idx] = 0.f;
  if (idx < NB * NHEADS * HC)      S[idx]   = 0.f;
}

// ---------------- kernel 0b: x [n][c][l] f32 -> xT [n][l][c] fp8 ----------------
__global__ __launch_bounds__(256)
void k_transpose(const float* __restrict__ x, unsigned char* __restrict__ xT) {
  __shared__ float tile[64][65];
  int b = blockIdx.x;
  int ct = b & 3;
  int lt = (b >> 2) & 255;
  int n  = b >> 10;
  int c0 = ct * 64, l0 = lt * 64;
  int t = threadIdx.x;
  int li = t & 63, cr = t >> 6;
  const float* xp = x + (size_t)n * CCH * LSP;
#pragma unroll
  for (int i = 0; i < 16; ++i) {
    int ci = cr * 16 + i;
    tile[ci][li] = xp[(size_t)(c0 + ci) * LSP + l0 + li];
  }
  __syncthreads();
  int cq = t & 15, lg = t >> 4;   // 16 col-quads x 16 l-groups (4 l each)
  unsigned char* xo = xT + ((size_t)n * LSP + l0) * CCH + c0;
#pragma unroll
  for (int i = 0; i < 4; ++i) {
    int l = lg * 4 + i;
    unsigned pk = 0;
#pragma unroll
    for (int j = 0; j < 4; ++j)
      pk |= ((unsigned)f2fp8(tile[cq * 4 + j][l])) << (8 * j);
    *(unsigned*)&xo[(size_t)l * CCH + cq * 4] = pk;
  }
}

// ---------------- kernel 1: fused QKV, fp8 staging GEMM, xt double-buffer ----------------
// grid 256: bid = h*32 + (n*4 + q2); 8 h-siblings share bid%8 -> one XCD (x L2-shared).
// 8 waves (2/SIMD) = rh{0,1} x pq{0..3}, wave tile 48 rows x 32 px, fp8 frags (b64).
// rh0 rows 0-47: k(32)+v(0-15) swapped mfma(x,W); rh1: v(16-31) swapped + q(32) normal.
// xt dbuf: stage(t+2) issued after barrier1 of tile t -> full-tile DMA window; counted
// per-role vmcnt (rh0 4 / rh1 12; never a fresh drain). Strips/ctx/q-softmax: bf16/f32.
// 16B-granular XOR swizzle keeps b64 pairs intact (rule 21 both-sides involution).
__global__ __launch_bounds__(512)
void k_fused(const unsigned char* __restrict__ xT,
             const unsigned char* __restrict__ Wb, const float* __restrict__ bb,
             unsigned short* __restrict__ qbuf, float* __restrict__ ctx,
             float* __restrict__ S) {
  __shared__ unsigned char wlds[96 * 256];        // 24 KiB (staged once)
  __shared__ unsigned char xt[2][128 * 256];      // 64 KiB dbuf
  __shared__ unsigned short ekst[2][32][136];     // 17 KiB exp(k) strips, dbuf
  __shared__ unsigned short vst[2][32][136];      // 17 KiB v strips, dbuf

  int bid = (int)blockIdx.x;
  int h = bid >> 5;
  int r5 = bid & 31;
  int n = r5 >> 2, q2 = r5 & 3;
  int l0 = q2 << 12;
  int nh = n * NHEADS + h;
  int tid = threadIdx.x;
  int wid = tid >> 6, lane = tid & 63;
  int r16 = lane & 15, kg = lane >> 4;
  int rh = wid >> 2;          // row half (48 rows)
  int pq = wid & 3;           // px quarter (32 px)

  const unsigned char* xTn = xT + ((size_t)n << 14) * CCH;
  const unsigned char* Wh = Wb + (size_t)h * 96 * CCH;

  // stage 128px x 256ch fp8 tile: 32 x 1KiB pieces, 4/wave; dest linear,
  // source 16B-chunk XOR-swizzled (both-sides involution, rule 21)
  auto stage_xt = [&](int buf, int tt) {
    int lb = l0 + tt * 128;
#pragma unroll
    for (int i = 0; i < 4; ++i) {
      int p = wid * 4 + i;                   // 0..31
      int px = p * 4 + (lane >> 4);
      int c16 = lane & 15;
      gload_lds16(xTn + ((size_t)(lb + px) << 8) + ((c16 ^ (px & 7)) << 4),
                  &xt[buf][p * 1024]);
    }
  };

  // prologue: W (24 pieces, 3/wave) + tiles 0,1
#pragma unroll
  for (int i = 0; i < 3; ++i) {
    int p = wid * 3 + i;                     // 0..23
    int row = p * 4 + (lane >> 4);
    int c16 = lane & 15;
    gload_lds16(Wh + ((size_t)row << 8) + ((c16 ^ (row & 7)) << 4), &wlds[p * 1024]);
  }
  stage_xt(0, 0);
  stage_xt(1, 1);

  float bw[3];
#pragma unroll
  for (int m = 0; m < 3; ++m) bw[m] = bb[h * 96 + rh * 48 + m * 16 + r16];
  float bq[2][4];
#pragma unroll
  for (int m = 0; m < 2; ++m)
#pragma unroll
    for (int r = 0; r < 4; ++r) bq[m][r] = bb[h * 96 + 64 + m * 16 + kg * 4 + r];

  f32x4 actx = {0.f, 0.f, 0.f, 0.f};   // quadrant (ckf=rh, cvf=pq&1), K-half pq>>1
  float sk0 = 0.f, sk1 = 0.f;

  asm volatile("s_waitcnt vmcnt(4)" ::: "memory");   // W + tile0 done; tile1 in flight
  __builtin_amdgcn_sched_barrier(0);
  __builtin_amdgcn_s_barrier();
  __builtin_amdgcn_sched_barrier(0);

  const int base_w = (rh * 48 + r16) * 256;
  const int base_x = (pq * 32 + r16) * 256;
  int kh = pq >> 1, cvf = pq & 1;

  for (int t = 0; t < NT; ++t) {
    int cur = t & 1, sb = t & 1, pb = sb ^ 1;
    // ---- ctx MFMA on previous tile's strips (bf16, one tile behind) ----
    if (t) {
#pragma unroll
      for (int ks = 0; ks < 2; ++ks) {
        int col = kh * 64 + ks * 32 + kg * 8;
        short8 a = *(const short8*)&ekst[pb][rh * 16 + r16][col];
        short8 b = *(const short8*)&vst[pb][cvf * 16 + r16][col];
        actx = __builtin_amdgcn_mfma_f32_16x16x32_bf16(a, b, actx, 0, 0, 0);
      }
    }
    // ---- K-loop: 48 rows x 32 px, fp8 frags (5 b64 reads -> 6 MFMA per kk) ----
    f32x4 acc[3][2];
#pragma unroll
    for (int m = 0; m < 3; ++m) { acc[m][0] = (f32x4){0,0,0,0}; acc[m][1] = (f32x4){0,0,0,0}; }
    const unsigned char* xb = &xt[cur][0];
#pragma unroll
    for (int kk = 0; kk < 8; ++kk) {
      int sw = (((kk * 2 + (kg >> 1)) ^ (r16 & 7)) << 4) + ((kg & 1) << 3);
      ll wf0 = *(const ll*)&wlds[base_w + sw];
      ll wf1 = *(const ll*)&wlds[base_w + 4096 + sw];
      ll wf2 = *(const ll*)&wlds[base_w + 8192 + sw];
      ll xf0 = *(const ll*)&xb[base_x + sw];
      ll xf1 = *(const ll*)&xb[base_x + 4096 + sw];
      if (rh == 0) {
        acc[0][0] = __builtin_amdgcn_mfma_f32_16x16x32_fp8_fp8(xf0, wf0, acc[0][0], 0, 0, 0);
        acc[0][1] = __builtin_amdgcn_mfma_f32_16x16x32_fp8_fp8(xf1, wf0, acc[0][1], 0, 0, 0);
        acc[1][0] = __builtin_amdgcn_mfma_f32_16x16x32_fp8_fp8(xf0, wf1, acc[1][0], 0, 0, 0);
        acc[1][1] = __builtin_amdgcn_mfma_f32_16x16x32_fp8_fp8(xf1, wf1, acc[1][1], 0, 0, 0);
        acc[2][0] = __builtin_amdgcn_mfma_f32_16x16x32_fp8_fp8(xf0, wf2, acc[2][0], 0, 0, 0);
        acc[2][1] = __builtin_amdgcn_mfma_f32_16x16x32_fp8_fp8(xf1, wf2, acc[2][1], 0, 0, 0);
      } else {
        acc[0][0] = __builtin_amdgcn_mfma_f32_16x16x32_fp8_fp8(xf0, wf0, acc[0][0], 0, 0, 0);
        acc[0][1] = __builtin_amdgcn_mfma_f32_16x16x32_fp8_fp8(xf1, wf0, acc[0][1], 0, 0, 0);
        acc[1][0] = __builtin_amdgcn_mfma_f32_16x16x32_fp8_fp8(wf1, xf0, acc[1][0], 0, 0, 0);
        acc[1][1] = __builtin_amdgcn_mfma_f32_16x16x32_fp8_fp8(wf1, xf1, acc[1][1], 0, 0, 0);
        acc[2][0] = __builtin_amdgcn_mfma_f32_16x16x32_fp8_fp8(wf2, xf0, acc[2][0], 0, 0, 0);
        acc[2][1] = __builtin_amdgcn_mfma_f32_16x16x32_fp8_fp8(wf2, xf1, acc[2][1], 0, 0, 0);
      }
    }
    __builtin_amdgcn_s_barrier();          // barrier1: all waves done reading xt[cur]
    if (t + 2 < NT) stage_xt(cur, t + 2);  // refill freed buffer; full-tile DMA window

    // ---- epilogue (wave-local); acc * 1/64 undoes W pre-scale ----
    if (rh == 0) {
#pragma unroll
      for (int nf = 0; nf < 2; ++nf) {
        int col = pq * 32 + nf * 16 + kg * 4;
#pragma unroll
        for (int m = 0; m < 2; ++m) {       // k rows -> exp strips + S
          float e0 = __expf(acc[m][nf][0] * WSC + bw[m]);
          float e1 = __expf(acc[m][nf][1] * WSC + bw[m]);
          float e2 = __expf(acc[m][nf][2] * WSC + bw[m]);
          float e3 = __expf(acc[m][nf][3] * WSC + bw[m]);
          if (m == 0) sk0 += e0 + e1 + e2 + e3; else sk1 += e0 + e1 + e2 + e3;
          uint2 u = {cvt_pk_bf16(e0, e1), cvt_pk_bf16(e2, e3)};
          *(uint2*)&ekst[sb][m * 16 + r16][col] = u;
        }
        {                                    // v rows 0-15
          float v0 = acc[2][nf][0] * WSC + bw[2], v1 = acc[2][nf][1] * WSC + bw[2];
          float v2 = acc[2][nf][2] * WSC + bw[2], v3 = acc[2][nf][3] * WSC + bw[2];
          uint2 u = {cvt_pk_bf16(v0, v1), cvt_pk_bf16(v2, v3)};
          *(uint2*)&vst[sb][r16][col] = u;
        }
      }
    } else {
#pragma unroll
      for (int nf = 0; nf < 2; ++nf) {
        int col = pq * 32 + nf * 16 + kg * 4;
        {                                    // v rows 16-31
          float v0 = acc[0][nf][0] * WSC + bw[0], v1 = acc[0][nf][1] * WSC + bw[0];
          float v2 = acc[0][nf][2] * WSC + bw[0], v3 = acc[0][nf][3] * WSC + bw[0];
          uint2 u = {cvt_pk_bf16(v0, v1), cvt_pk_bf16(v2, v3)};
          *(uint2*)&vst[sb][16 + r16][col] = u;
        }
        // q: softmax over 32 ck, wholly in-wave (8 in-lane + shfl 16,32)
        float ea[4], eb[4];
        float s = 0.f;
#pragma unroll
        for (int r = 0; r < 4; ++r) {
          ea[r] = __expf(acc[1][nf][r] * WSC + bq[0][r]);
          eb[r] = __expf(acc[2][nf][r] * WSC + bq[1][r]);
          s += ea[r] + eb[r];
        }
        s += __shfl_xor(s, 16);
        s += __shfl_xor(s, 32);
        float inv = 1.f / s;
        int l = l0 + t * 128 + pq * 32 + nf * 16 + r16;
        unsigned short* qb = qbuf + (((size_t)nh * LSP + l) << 5);
        uint2 u0 = {cvt_pk_bf16(ea[0] * inv, ea[1] * inv), cvt_pk_bf16(ea[2] * inv, ea[3] * inv)};
        uint2 u1 = {cvt_pk_bf16(eb[0] * inv, eb[1] * inv), cvt_pk_bf16(eb[2] * inv, eb[3] * inv)};
        *(uint2*)&qb[kg * 4]      = u0;
        *(uint2*)&qb[16 + kg * 4] = u1;
      }
    }
    // barrier2: strips visible; next tile's buffer staged (counted, per-role)
    asm volatile("s_waitcnt lgkmcnt(0)" ::: "memory");
    __builtin_amdgcn_sched_barrier(0);
    if (t < NT - 2) {
      if (rh == 0) { asm volatile("s_waitcnt vmcnt(4)" ::: "memory"); }
      else         { asm volatile("s_waitcnt vmcnt(12)" ::: "memory"); }
    } else if (t == NT - 2) {
      if (rh == 0) { asm volatile("s_waitcnt vmcnt(0)" ::: "memory"); }
      else         { asm volatile("s_waitcnt vmcnt(8)" ::: "memory"); }
    }
    __builtin_amdgcn_sched_barrier(0);
    __builtin_amdgcn_s_barrier();
    __builtin_amdgcn_sched_barrier(0);
  }

  // final ctx on last tile's strips
#pragma unroll
  for (int ks = 0; ks < 2; ++ks) {
    int col = kh * 64 + ks * 32 + kg * 8;
    short8 a = *(const short8*)&ekst[(NT - 1) & 1][rh * 16 + r16][col];
    short8 b = *(const short8*)&vst[(NT - 1) & 1][cvf * 16 + r16][col];
    actx = __builtin_amdgcn_mfma_f32_16x16x32_bf16(a, b, actx, 0, 0, 0);
  }
  // flush: ctx quadrant + S rows
  float* cp = ctx + ((size_t)nh << 10);
#pragma unroll
  for (int r = 0; r < 4; ++r)
    atomicAdd(&cp[(rh * 16 + kg * 4 + r) * HC + cvf * 16 + r16], actx[r]);
  if (rh == 0) {
    float s0 = sk0, s1 = sk1;
    s0 += __shfl_xor(s0, 16); s0 += __shfl_xor(s0, 32);
    s1 += __shfl_xor(s1, 16); s1 += __shfl_xor(s1, 32);
    if (kg == 0) {
      atomicAdd(&S[nh * HC + r16], s0);
      atomicAdd(&S[nh * HC + 16 + r16], s1);
    }
  }
}

// ---------------- kernel 2: ctx/S, transpose, -> bf16 ----------------
__global__ void k_norm(const float* __restrict__ ctx, const float* __restrict__ S,
                       unsigned short* __restrict__ ctxT) {
  int idx = blockIdx.x * 256 + threadIdx.x;  // 65536 = [n][h][ck][cv]
  int cv = idx & 31, ck = (idx >> 5) & 31, nh = idx >> 10;
  float v = ctx[idx] / S[(nh << 5) + ck];
  ctxT[(nh << 10) + (cv << 5) + ck] = f2bf(v);
}

// ---------------- kernel 3: att = ctxT (32x32) x q_soft (32 x L) + residual ----------------
__global__ __launch_bounds__(256)
void k_att(const float* __restrict__ x, const unsigned short* __restrict__ qbuf,
           const unsigned short* __restrict__ ctxT, float* __restrict__ out) {
  int b = blockIdx.x;
  int lc = b & 63;
  int nh = b >> 6;
  int h = nh & 7, n = nh >> 3;
  int tid = threadIdx.x, wid = tid >> 6, lane = tid & 63;
  int r16 = lane & 15, kg = lane >> 4;
  int lw = lc * 256 + wid * 64;

  const unsigned short* cp = ctxT + ((size_t)nh << 10);
  short8 a0 = *(const short8*)&cp[(r16 << 5) + kg * 8];          // A[cv][ck], cv 0-15
  short8 a1 = *(const short8*)&cp[((16 + r16) << 5) + kg * 8];   // cv 16-31
  const unsigned short* qb = qbuf + (((size_t)nh * LSP) << 5);
  const float* xp = x   + ((size_t)n * CCH + (size_t)h * HC) * LSP;
  float*       op = out + ((size_t)n * CCH + (size_t)h * HC) * LSP;

#pragma unroll
  for (int t = 0; t < 4; ++t) {
    int l = lw + t * 16;
    short8 bf = *(const short8*)&qb[((size_t)(l + r16) << 5) + kg * 8];  // softmaxed q [l][ck]
    f32x4 d0 = {0, 0, 0, 0}, d1 = {0, 0, 0, 0};
    d0 = __builtin_amdgcn_mfma_f32_16x16x32_bf16(a0, bf, d0, 0, 0, 0);
    d1 = __builtin_amdgcn_mfma_f32_16x16x32_bf16(a1, bf, d1, 0, 0, 0);
#pragma unroll
    for (int r = 0; r < 4; ++r) {
      int cv = kg * 4 + r;
      int li = l + r16;
      op[(size_t)cv * LSP + li]        = d0[r] + xp[(size_t)cv * LSP + li];
      op[(size_t)(cv + 16) * LSP + li] = d1[r] + xp[(size_t)(cv + 16) * LSP + li];
    }
  }
}

extern "C" void kernel_launch(void* const* d_in, const int* in_sizes, int n_in,
                              void* d_out, int out_size, void* d_ws, size_t ws_size,
                              hipStream_t stream) {
  (void)in_sizes; (void)n_in; (void)out_size; (void)ws_size;
  const float* x  = (const float*)d_in[0];
  const float* Wk = (const float*)d_in[1];
  const float* bk = (const float*)d_in[2];
  const float* Wq = (const float*)d_in[3];
  const float* bq = (const float*)d_in[4];
  const float* Wv = (const float*)d_in[5];
  const float* bv = (const float*)d_in[6];
  float* out = (float*)d_out;

  char* ws = (char*)d_ws;
  unsigned char*  Wb   = (unsigned char*)(ws + 0);           //    196608 (fp8, x64-scaled)
  float*          bbp  = (float*)(ws + 196608);              //      3072
  float*          ctx  = (float*)(ws + 199680);              //    262144
  unsigned short* ctxT = (unsigned short*)(ws + 461824);     //    131072
  float*          S    = (float*)(ws + 592896);              //      8192
  unsigned short* qbuf = (unsigned short*)(ws + 601088);     //  67108864 (bf16)
  unsigned char*  xT   = (unsigned char*)(ws + 67709952);    //  33554432 (fp8) -> 101264384

  k_prep<<<768, 256, 0, stream>>>(Wk, bk, Wq, bq, Wv, bv, Wb, bbp, ctx, S);
  k_transpose<<<NB * 256 * 4, 256, 0, stream>>>(x, xT);
  k_fused<<<256, 512, 0, stream>>>(xT, Wb, bbp, qbuf, ctx, S);
  k_norm<<<256, 256, 0, stream>>>(ctx, S, ctxT);
  k_att<<<NB * NHEADS * 64, 256, 0, stream>>>(x, qbuf, ctxT, out);
}

// Round 15
// 188.174 us; speedup vs baseline: 1.6455x; 1.0302x over previous
//
#include <hip/hip_runtime.h>

// EfficientAttention: N=8, C=256, H=W=128 (L=16384), HEADS=8, hc=32
// out = x + att,  att[n,h,cv,l] = sum_ck (ctx[ck,cv]/S[ck]) * softmax_ck(q)[ck,l]
// ctx[ck,cv] = sum_l exp(k[ck,l]) * v[cv,l],  S[ck] = sum_l exp(k[ck,l])
//
// R15 = R14 (fp8 staging GEMM, xt dbuf, counted vmcnt) +
//   (1) 4-bit XOR swizzle on stage/fragment (4-way -> 2-way, free),
//   (2) strip chunk-XOR (ctx b128 reads 8-way -> ~2-way),
//   (3) q & ctxT in fp8 -> k_att uses fp8 MFMA (q traffic halved),
//   (4) s_setprio around the K-loop MFMA cluster.

typedef __attribute__((ext_vector_type(8))) short short8;
typedef __attribute__((ext_vector_type(4))) float f32x4;
typedef long long ll;

#define NB     8
#define CCH    256
#define LSP    16384
#define NHEADS 8
#define HC     32
#define NT     32     // 128-px tiles per block (4096-px quarter-L)
#define WSC    0.015625f   // 1/64: undo W pre-scale

__device__ __forceinline__ unsigned short f2bf(float f) {
  union { float f; unsigned u; } v; v.f = f;
  unsigned r = v.u + 0x7fffu + ((v.u >> 16) & 1u);   // RNE
  return (unsigned short)(r >> 16);
}
__device__ __forceinline__ unsigned cvt_pk_bf16(float lo, float hi) {
  unsigned r;
  asm("v_cvt_pk_bf16_f32 %0, %1, %2" : "=v"(r) : "v"(lo), "v"(hi));
  return r;
}
// 4 floats -> 4 fp8 e4m3 packed in a u32 (HW cvt, RNE)
__device__ __forceinline__ unsigned cvt4_fp8(float a, float b, float c, float d) {
  unsigned r;
  asm("v_cvt_pk_fp8_f32 %0, %1, %2\n\t"
      "v_cvt_pk_fp8_f32 %0, %3, %4 op_sel:[0,0,1]"
      : "=v"(r) : "v"(a), "v"(b), "v"(c), "v"(d));
  return r;
}
// float -> fp8 e4m3fn (software, for once-only prep kernels)
__device__ __forceinline__ unsigned char f2fp8(float f) {
  union { float f; unsigned u; } v; v.f = f;
  unsigned s = (v.u >> 24) & 0x80u;
  unsigned x = v.u & 0x7FFFFFFFu;
  if (x < 0x3C800000u) {
    float a = fabsf(f);
    int q = (int)rintf(a * 512.f);
    return (unsigned char)(s | (unsigned)q);
  }
  unsigned r = x + 0xFFFFFu + ((x >> 20) & 1u);
  unsigned e = r >> 23;
  unsigned m = (r >> 20) & 7u;
  int fe = (int)e - 120;
  if (fe > 15 || (fe == 15 && m == 7)) return (unsigned char)(s | 0x7Eu);
  return (unsigned char)(s | ((unsigned)fe << 3) | m);
}
__device__ __forceinline__ void gload_lds16(const unsigned char* g, unsigned char* l) {
  __builtin_amdgcn_global_load_lds(
      (const __attribute__((address_space(1))) unsigned int*)g,
      (__attribute__((address_space(3))) unsigned int*)l, 16, 0, 0);
}
// strip byte offset with 16B-chunk XOR swizzle (involution on low 3 chunk bits)
__device__ __forceinline__ int strip_off(int row, int colsh) {
  int byte = colsh * 2;
  int chunk = byte >> 4;
  return row * 272 + (((chunk ^ (row & 7)) << 4) | (byte & 15));
}

// ---------------- kernel 0: weights -> fp8 (x64 pre-scale) head-grouped [k32|v32|q32] ------
__global__ void k_prep(const float* __restrict__ Wk, const float* __restrict__ bk,
                       const float* __restrict__ Wq, const float* __restrict__ bq,
                       const float* __restrict__ Wv, const float* __restrict__ bv,
                       unsigned char* __restrict__ Wb, float* __restrict__ bb,
                       float* __restrict__ ctx, float* __restrict__ S) {
  int idx = blockIdx.x * 256 + threadIdx.x;
  if (idx < NHEADS * 96 * CCH) {
    int c = idx & (CCH - 1);
    int row = (idx >> 8) % 96;
    int h = idx / (96 * CCH);
    int ch = h * HC;
    float val;
    if (row < HC)          val = Wk[(ch + row) * CCH + c];
    else if (row < 2 * HC) val = Wv[(ch + row - HC) * CCH + c];
    else                   val = Wq[(ch + row - 2 * HC) * CCH + c];
    Wb[idx] = f2fp8(val * 64.f);
  }
  if (idx < NHEADS * 96) {
    int row = idx % 96, h = idx / 96, ch = h * HC;
    float val;
    if (row < HC)          val = bk[ch + row];
    else if (row < 2 * HC) val = bv[ch + row - HC];
    else                   val = bq[ch + row - 2 * HC];
    bb[idx] = val;
  }
  if (idx < NB * NHEADS * HC * HC) ctx[idx] = 0.f;
  if (idx < NB * NHEADS * HC)      S[idx]   = 0.f;
}

// ---------------- kernel 0b: x [n][c][l] f32 -> xT [n][l][c] fp8 ----------------
__global__ __launch_bounds__(256)
void k_transpose(const float* __restrict__ x, unsigned char* __restrict__ xT) {
  __shared__ float tile[64][65];
  int b = blockIdx.x;
  int ct = b & 3;
  int lt = (b >> 2) & 255;
  int n  = b >> 10;
  int c0 = ct * 64, l0 = lt * 64;
  int t = threadIdx.x;
  int li = t & 63, cr = t >> 6;
  const float* xp = x + (size_t)n * CCH * LSP;
#pragma unroll
  for (int i = 0; i < 16; ++i) {
    int ci = cr * 16 + i;
    tile[ci][li] = xp[(size_t)(c0 + ci) * LSP + l0 + li];
  }
  __syncthreads();
  int cq = t & 15, lg = t >> 4;
  unsigned char* xo = xT + ((size_t)n * LSP + l0) * CCH + c0;
#pragma unroll
  for (int i = 0; i < 4; ++i) {
    int l = lg * 4 + i;
    unsigned pk = cvt4_fp8(tile[cq * 4][l], tile[cq * 4 + 1][l],
                           tile[cq * 4 + 2][l], tile[cq * 4 + 3][l]);
    *(unsigned*)&xo[(size_t)l * CCH + cq * 4] = pk;
  }
}

// ---------------- kernel 1: fused QKV, fp8 staging GEMM, xt double-buffer ----------------
// grid 256: bid = h*32 + (n*4 + q2); 8 h-siblings share bid%8 -> one XCD (x L2-shared).
// 8 waves (2/SIMD) = rh{0,1} x pq{0..3}, wave tile 48 rows x 32 px, fp8 frags (b64).
// 4-bit XOR swizzle on stage source / fragment reads -> exact 2-way (free).
// Strips bf16 with chunk-XOR (ctx reads ~2-way). q stored softmaxed fp8.
__global__ __launch_bounds__(512)
void k_fused(const unsigned char* __restrict__ xT,
             const unsigned char* __restrict__ Wb, const float* __restrict__ bb,
             unsigned char* __restrict__ qbuf, float* __restrict__ ctx,
             float* __restrict__ S) {
  __shared__ unsigned char wlds[96 * 256];                  // 24 KiB (staged once)
  __shared__ unsigned char xt[2][128 * 256];                // 64 KiB dbuf
  __shared__ __align__(16) unsigned char ekst[2][32 * 272]; // 17 KiB exp(k) strips
  __shared__ __align__(16) unsigned char vst[2][32 * 272];  // 17 KiB v strips

  int bid = (int)blockIdx.x;
  int h = bid >> 5;
  int r5 = bid & 31;
  int n = r5 >> 2, q2 = r5 & 3;
  int l0 = q2 << 12;
  int nh = n * NHEADS + h;
  int tid = threadIdx.x;
  int wid = tid >> 6, lane = tid & 63;
  int r16 = lane & 15, kg = lane >> 4;
  int rh = wid >> 2;          // row half (48 rows)
  int pq = wid & 3;           // px quarter (32 px)

  const unsigned char* xTn = xT + ((size_t)n << 14) * CCH;
  const unsigned char* Wh = Wb + (size_t)h * 96 * CCH;

  // stage 128px x 256ch fp8 tile: 32 x 1KiB pieces, 4/wave; dest linear,
  // source 16B-chunk XOR (4-bit involution, rule 21)
  auto stage_xt = [&](int buf, int tt) {
    int lb = l0 + tt * 128;
#pragma unroll
    for (int i = 0; i < 4; ++i) {
      int p = wid * 4 + i;                   // 0..31
      int px = p * 4 + (lane >> 4);
      int c16 = lane & 15;
      gload_lds16(xTn + ((size_t)(lb + px) << 8) + ((c16 ^ (px & 15)) << 4),
                  &xt[buf][p * 1024]);
    }
  };

  // prologue: W (24 pieces, 3/wave) + tiles 0,1
#pragma unroll
  for (int i = 0; i < 3; ++i) {
    int p = wid * 3 + i;
    int row = p * 4 + (lane >> 4);
    int c16 = lane & 15;
    gload_lds16(Wh + ((size_t)row << 8) + ((c16 ^ (row & 15)) << 4), &wlds[p * 1024]);
  }
  stage_xt(0, 0);
  stage_xt(1, 1);

  float bw[3];
#pragma unroll
  for (int m = 0; m < 3; ++m) bw[m] = bb[h * 96 + rh * 48 + m * 16 + r16];
  float bq[2][4];
#pragma unroll
  for (int m = 0; m < 2; ++m)
#pragma unroll
    for (int r = 0; r < 4; ++r) bq[m][r] = bb[h * 96 + 64 + m * 16 + kg * 4 + r];

  f32x4 actx = {0.f, 0.f, 0.f, 0.f};   // quadrant (ckf=rh, cvf=pq&1), K-half pq>>1
  float sk0 = 0.f, sk1 = 0.f;

  asm volatile("s_waitcnt vmcnt(4)" ::: "memory");   // W + tile0 done; tile1 in flight
  __builtin_amdgcn_sched_barrier(0);
  __builtin_amdgcn_s_barrier();
  __builtin_amdgcn_sched_barrier(0);

  const int base_w = (rh * 48 + r16) * 256;
  const int base_x = (pq * 32 + r16) * 256;
  int kh = pq >> 1, cvf = pq & 1;

  for (int t = 0; t < NT; ++t) {
    int cur = t & 1, sb = t & 1, pb = sb ^ 1;
    // ---- ctx MFMA on previous tile's strips (bf16, one tile behind) ----
    if (t) {
#pragma unroll
      for (int ks = 0; ks < 2; ++ks) {
        int colsh = kh * 64 + ks * 32 + kg * 8;
        short8 a = *(const short8*)&ekst[pb][strip_off(rh * 16 + r16, colsh)];
        short8 b = *(const short8*)&vst[pb][strip_off(cvf * 16 + r16, colsh)];
        actx = __builtin_amdgcn_mfma_f32_16x16x32_bf16(a, b, actx, 0, 0, 0);
      }
    }
    // ---- K-loop: 48 rows x 32 px, fp8 frags (5 b64 reads -> 6 MFMA per kk) ----
    f32x4 acc[3][2];
#pragma unroll
    for (int m = 0; m < 3; ++m) { acc[m][0] = (f32x4){0,0,0,0}; acc[m][1] = (f32x4){0,0,0,0}; }
    const unsigned char* xb = &xt[cur][0];
    __builtin_amdgcn_s_setprio(1);
#pragma unroll
    for (int kk = 0; kk < 8; ++kk) {
      int sw = (((kk * 2 + (kg >> 1)) ^ r16) << 4) + ((kg & 1) << 3);
      ll wf0 = *(const ll*)&wlds[base_w + sw];
      ll wf1 = *(const ll*)&wlds[base_w + 4096 + sw];
      ll wf2 = *(const ll*)&wlds[base_w + 8192 + sw];
      ll xf0 = *(const ll*)&xb[base_x + sw];
      ll xf1 = *(const ll*)&xb[base_x + 4096 + sw];
      if (rh == 0) {
        acc[0][0] = __builtin_amdgcn_mfma_f32_16x16x32_fp8_fp8(xf0, wf0, acc[0][0], 0, 0, 0);
        acc[0][1] = __builtin_amdgcn_mfma_f32_16x16x32_fp8_fp8(xf1, wf0, acc[0][1], 0, 0, 0);
        acc[1][0] = __builtin_amdgcn_mfma_f32_16x16x32_fp8_fp8(xf0, wf1, acc[1][0], 0, 0, 0);
        acc[1][1] = __builtin_amdgcn_mfma_f32_16x16x32_fp8_fp8(xf1, wf1, acc[1][1], 0, 0, 0);
        acc[2][0] = __builtin_amdgcn_mfma_f32_16x16x32_fp8_fp8(xf0, wf2, acc[2][0], 0, 0, 0);
        acc[2][1] = __builtin_amdgcn_mfma_f32_16x16x32_fp8_fp8(xf1, wf2, acc[2][1], 0, 0, 0);
      } else {
        acc[0][0] = __builtin_amdgcn_mfma_f32_16x16x32_fp8_fp8(xf0, wf0, acc[0][0], 0, 0, 0);
        acc[0][1] = __builtin_amdgcn_mfma_f32_16x16x32_fp8_fp8(xf1, wf0, acc[0][1], 0, 0, 0);
        acc[1][0] = __builtin_amdgcn_mfma_f32_16x16x32_fp8_fp8(wf1, xf0, acc[1][0], 0, 0, 0);
        acc[1][1] = __builtin_amdgcn_mfma_f32_16x16x32_fp8_fp8(wf1, xf1, acc[1][1], 0, 0, 0);
        acc[2][0] = __builtin_amdgcn_mfma_f32_16x16x32_fp8_fp8(wf2, xf0, acc[2][0], 0, 0, 0);
        acc[2][1] = __builtin_amdgcn_mfma_f32_16x16x32_fp8_fp8(wf2, xf1, acc[2][1], 0, 0, 0);
      }
    }
    __builtin_amdgcn_s_setprio(0);
    __builtin_amdgcn_s_barrier();          // barrier1: all waves done reading xt[cur]
    if (t + 2 < NT) stage_xt(cur, t + 2);  // refill freed buffer; full-tile DMA window

    // ---- epilogue (wave-local); acc * 1/64 undoes W pre-scale ----
    if (rh == 0) {
#pragma unroll
      for (int nf = 0; nf < 2; ++nf) {
        int col = pq * 32 + nf * 16 + kg * 4;
#pragma unroll
        for (int m = 0; m < 2; ++m) {       // k rows -> exp strips + S
          float e0 = __expf(acc[m][nf][0] * WSC + bw[m]);
          float e1 = __expf(acc[m][nf][1] * WSC + bw[m]);
          float e2 = __expf(acc[m][nf][2] * WSC + bw[m]);
          float e3 = __expf(acc[m][nf][3] * WSC + bw[m]);
          if (m == 0) sk0 += e0 + e1 + e2 + e3; else sk1 += e0 + e1 + e2 + e3;
          uint2 u = {cvt_pk_bf16(e0, e1), cvt_pk_bf16(e2, e3)};
          *(uint2*)&ekst[sb][strip_off(m * 16 + r16, col)] = u;
        }
        {                                    // v rows 0-15
          float v0 = acc[2][nf][0] * WSC + bw[2], v1 = acc[2][nf][1] * WSC + bw[2];
          float v2 = acc[2][nf][2] * WSC + bw[2], v3 = acc[2][nf][3] * WSC + bw[2];
          uint2 u = {cvt_pk_bf16(v0, v1), cvt_pk_bf16(v2, v3)};
          *(uint2*)&vst[sb][strip_off(r16, col)] = u;
        }
      }
    } else {
#pragma unroll
      for (int nf = 0; nf < 2; ++nf) {
        int col = pq * 32 + nf * 16 + kg * 4;
        {                                    // v rows 16-31
          float v0 = acc[0][nf][0] * WSC + bw[0], v1 = acc[0][nf][1] * WSC + bw[0];
          float v2 = acc[0][nf][2] * WSC + bw[0], v3 = acc[0][nf][3] * WSC + bw[0];
          uint2 u = {cvt_pk_bf16(v0, v1), cvt_pk_bf16(v2, v3)};
          *(uint2*)&vst[sb][strip_off(16 + r16, col)] = u;
        }
        // q: softmax over 32 ck, wholly in-wave (8 in-lane + shfl 16,32); store fp8
        float ea[4], eb[4];
        float s = 0.f;
#pragma unroll
        for (int r = 0; r < 4; ++r) {
          ea[r] = __expf(acc[1][nf][r] * WSC + bq[0][r]);
          eb[r] = __expf(acc[2][nf][r] * WSC + bq[1][r]);
          s += ea[r] + eb[r];
        }
        s += __shfl_xor(s, 16);
        s += __shfl_xor(s, 32);
        float inv = 1.f / s;
        int l = l0 + t * 128 + pq * 32 + nf * 16 + r16;
        unsigned char* qb = qbuf + (((size_t)nh * LSP + l) << 5);
        unsigned u0 = cvt4_fp8(ea[0] * inv, ea[1] * inv, ea[2] * inv, ea[3] * inv);
        unsigned u1 = cvt4_fp8(eb[0] * inv, eb[1] * inv, eb[2] * inv, eb[3] * inv);
        *(unsigned*)&qb[kg * 4]      = u0;
        *(unsigned*)&qb[16 + kg * 4] = u1;
      }
    }
    // barrier2: strips visible; next tile's buffer staged (counted, per-role)
    asm volatile("s_waitcnt lgkmcnt(0)" ::: "memory");
    __builtin_amdgcn_sched_barrier(0);
    if (t < NT - 2) {
      if (rh == 0) { asm volatile("s_waitcnt vmcnt(4)" ::: "memory"); }
      else         { asm volatile("s_waitcnt vmcnt(8)" ::: "memory"); }
    } else if (t == NT - 2) {
      if (rh == 0) { asm volatile("s_waitcnt vmcnt(0)" ::: "memory"); }
      else         { asm volatile("s_waitcnt vmcnt(4)" ::: "memory"); }
    }
    __builtin_amdgcn_sched_barrier(0);
    __builtin_amdgcn_s_barrier();
    __builtin_amdgcn_sched_barrier(0);
  }

  // final ctx on last tile's strips
#pragma unroll
  for (int ks = 0; ks < 2; ++ks) {
    int colsh = kh * 64 + ks * 32 + kg * 8;
    short8 a = *(const short8*)&ekst[(NT - 1) & 1][strip_off(rh * 16 + r16, colsh)];
    short8 b = *(const short8*)&vst[(NT - 1) & 1][strip_off(cvf * 16 + r16, colsh)];
    actx = __builtin_amdgcn_mfma_f32_16x16x32_bf16(a, b, actx, 0, 0, 0);
  }
  // flush: ctx quadrant + S rows
  float* cp = ctx + ((size_t)nh << 10);
#pragma unroll
  for (int r = 0; r < 4; ++r)
    atomicAdd(&cp[(rh * 16 + kg * 4 + r) * HC + cvf * 16 + r16], actx[r]);
  if (rh == 0) {
    float s0 = sk0, s1 = sk1;
    s0 += __shfl_xor(s0, 16); s0 += __shfl_xor(s0, 32);
    s1 += __shfl_xor(s1, 16); s1 += __shfl_xor(s1, 32);
    if (kg == 0) {
      atomicAdd(&S[nh * HC + r16], s0);
      atomicAdd(&S[nh * HC + 16 + r16], s1);
    }
  }
}

// ---------------- kernel 2: ctx/S, transpose, -> fp8 ----------------
__global__ void k_norm(const float* __restrict__ ctx, const float* __restrict__ S,
                       unsigned char* __restrict__ ctxT) {
  int idx = blockIdx.x * 256 + threadIdx.x;  // 65536 = [n][h][ck][cv]
  int cv = idx & 31, ck = (idx >> 5) & 31, nh = idx >> 10;
  float v = ctx[idx] / S[(nh << 5) + ck];
  ctxT[(nh << 10) + (cv << 5) + ck] = f2fp8(v);
}

// ---------------- kernel 3: att = ctxT (fp8) x q_soft (fp8) + residual ----------------
__global__ __launch_bounds__(256)
void k_att(const float* __restrict__ x, const unsigned char* __restrict__ qbuf,
           const unsigned char* __restrict__ ctxT, float* __restrict__ out) {
  int b = blockIdx.x;
  int lc = b & 63;
  int nh = b >> 6;
  int h = nh & 7, n = nh >> 3;
  int tid = threadIdx.x, wid = tid >> 6, lane = tid & 63;
  int r16 = lane & 15, kg = lane >> 4;
  int lw = lc * 256 + wid * 64;

  const unsigned char* cp = ctxT + ((size_t)nh << 10);
  ll a0 = *(const ll*)&cp[(r16 << 5) + kg * 8];          // A[cv][ck], cv 0-15
  ll a1 = *(const ll*)&cp[((16 + r16) << 5) + kg * 8];   // cv 16-31
  const unsigned char* qb = qbuf + (((size_t)nh * LSP) << 5);
  const float* xp = x   + ((size_t)n * CCH + (size_t)h * HC) * LSP;
  float*       op = out + ((size_t)n * CCH + (size_t)h * HC) * LSP;

#pragma unroll
  for (int t = 0; t < 4; ++t) {
    int l = lw + t * 16;
    ll bq = *(const ll*)&qb[((size_t)(l + r16) << 5) + kg * 8];  // softmaxed q [l][ck] fp8
    f32x4 d0 = {0, 0, 0, 0}, d1 = {0, 0, 0, 0};
    d0 = __builtin_amdgcn_mfma_f32_16x16x32_fp8_fp8(a0, bq, d0, 0, 0, 0);
    d1 = __builtin_amdgcn_mfma_f32_16x16x32_fp8_fp8(a1, bq, d1, 0, 0, 0);
#pragma unroll
    for (int r = 0; r < 4; ++r) {
      int cv = kg * 4 + r;
      int li = l + r16;
      op[(size_t)cv * LSP + li]        = d0[r] + xp[(size_t)cv * LSP + li];
      op[(size_t)(cv + 16) * LSP + li] = d1[r] + xp[(size_t)(cv + 16) * LSP + li];
    }
  }
}

extern "C" void kernel_launch(void* const* d_in, const int* in_sizes, int n_in,
                              void* d_out, int out_size, void* d_ws, size_t ws_size,
                              hipStream_t stream) {
  (void)in_sizes; (void)n_in; (void)out_size; (void)ws_size;
  const float* x  = (const float*)d_in[0];
  const float* Wk = (const float*)d_in[1];
  const float* bk = (const float*)d_in[2];
  const float* Wq = (const float*)d_in[3];
  const float* bq = (const float*)d_in[4];
  const float* Wv = (const float*)d_in[5];
  const float* bv = (const float*)d_in[6];
  float* out = (float*)d_out;

  char* ws = (char*)d_ws;
  unsigned char*  Wb   = (unsigned char*)(ws + 0);           //    196608 (fp8, x64-scaled)
  float*          bbp  = (float*)(ws + 196608);              //      3072
  float*          ctx  = (float*)(ws + 199680);              //    262144
  unsigned char*  ctxT = (unsigned char*)(ws + 461824);      //     32768 (fp8)
  float*          S    = (float*)(ws + 494592);              //      8192
  unsigned char*  qbuf = (unsigned char*)(ws + 502784);      //  33554432 (fp8)
  unsigned char*  xT   = (unsigned char*)(ws + 34057216);    //  33554432 (fp8) -> 67611648

  k_prep<<<768, 256, 0, stream>>>(Wk, bk, Wq, bq, Wv, bv, Wb, bbp, ctx, S);
  k_transpose<<<NB * 256 * 4, 256, 0, stream>>>(x, xT);
  k_fused<<<256, 512, 0, stream>>>(xT, Wb, bbp, qbuf, ctx, S);
  k_norm<<<256, 256, 0, stream>>>(ctx, S, ctxT);
  k_att<<<NB * NHEADS * 64, 256, 0, stream>>>(x, qbuf, ctxT, out);
}

// Round 16
// 186.758 us; speedup vs baseline: 1.6580x; 1.0076x over previous
//
#include <hip/hip_runtime.h>

// EfficientAttention: N=8, C=256, H=W=128 (L=16384), HEADS=8, hc=32
// out = x + att,  att[n,h,cv,l] = sum_ck (ctx[ck,cv]/S[ck]) * softmax_ck(q)[ck,l]
// ctx[ck,cv] = sum_l exp(k[ck,l]) * v[cv,l],  S[ck] = sum_l exp(k[ck,l])
//
// R16 = R14 k_fused verbatim (3-bit swizzles, plain [32][136] strips, no setprio --
// R15's strip chunk-XOR doubled bank conflicts: bank group (u+(c^u))%8 collapses to
// 4 values at c=0; R14's natural pitch-272 rotation was already ~conflict-free)
// + R15's proven-good pieces: q stored softmaxed fp8, ctxT fp8, fp8 k_att.

typedef __attribute__((ext_vector_type(8))) short short8;
typedef __attribute__((ext_vector_type(4))) float f32x4;
typedef long long ll;

#define NB     8
#define CCH    256
#define LSP    16384
#define NHEADS 8
#define HC     32
#define NT     32     // 128-px tiles per block (4096-px quarter-L)
#define WSC    0.015625f   // 1/64: undo W pre-scale

__device__ __forceinline__ unsigned short f2bf(float f) {
  union { float f; unsigned u; } v; v.f = f;
  unsigned r = v.u + 0x7fffu + ((v.u >> 16) & 1u);   // RNE
  return (unsigned short)(r >> 16);
}
__device__ __forceinline__ unsigned cvt_pk_bf16(float lo, float hi) {
  unsigned r;
  asm("v_cvt_pk_bf16_f32 %0, %1, %2" : "=v"(r) : "v"(lo), "v"(hi));
  return r;
}
// 4 floats -> 4 fp8 e4m3 packed in a u32 (HW cvt, RNE)
__device__ __forceinline__ unsigned cvt4_fp8(float a, float b, float c, float d) {
  unsigned r;
  asm("v_cvt_pk_fp8_f32 %0, %1, %2\n\t"
      "v_cvt_pk_fp8_f32 %0, %3, %4 op_sel:[0,0,1]"
      : "=v"(r) : "v"(a), "v"(b), "v"(c), "v"(d));
  return r;
}
// float -> fp8 e4m3fn (software, for once-only prep kernels)
__device__ __forceinline__ unsigned char f2fp8(float f) {
  union { float f; unsigned u; } v; v.f = f;
  unsigned s = (v.u >> 24) & 0x80u;
  unsigned x = v.u & 0x7FFFFFFFu;
  if (x < 0x3C800000u) {
    float a = fabsf(f);
    int q = (int)rintf(a * 512.f);
    return (unsigned char)(s | (unsigned)q);
  }
  unsigned r = x + 0xFFFFFu + ((x >> 20) & 1u);
  unsigned e = r >> 23;
  unsigned m = (r >> 20) & 7u;
  int fe = (int)e - 120;
  if (fe > 15 || (fe == 15 && m == 7)) return (unsigned char)(s | 0x7Eu);
  return (unsigned char)(s | ((unsigned)fe << 3) | m);
}
__device__ __forceinline__ void gload_lds16(const unsigned char* g, unsigned char* l) {
  __builtin_amdgcn_global_load_lds(
      (const __attribute__((address_space(1))) unsigned int*)g,
      (__attribute__((address_space(3))) unsigned int*)l, 16, 0, 0);
}

// ---------------- kernel 0: weights -> fp8 (x64 pre-scale) head-grouped [k32|v32|q32] ------
__global__ void k_prep(const float* __restrict__ Wk, const float* __restrict__ bk,
                       const float* __restrict__ Wq, const float* __restrict__ bq,
                       const float* __restrict__ Wv, const float* __restrict__ bv,
                       unsigned char* __restrict__ Wb, float* __restrict__ bb,
                       float* __restrict__ ctx, float* __restrict__ S) {
  int idx = blockIdx.x * 256 + threadIdx.x;
  if (idx < NHEADS * 96 * CCH) {
    int c = idx & (CCH - 1);
    int row = (idx >> 8) % 96;
    int h = idx / (96 * CCH);
    int ch = h * HC;
    float val;
    if (row < HC)          val = Wk[(ch + row) * CCH + c];
    else if (row < 2 * HC) val = Wv[(ch + row - HC) * CCH + c];
    else                   val = Wq[(ch + row - 2 * HC) * CCH + c];
    Wb[idx] = f2fp8(val * 64.f);
  }
  if (idx < NHEADS * 96) {
    int row = idx % 96, h = idx / 96, ch = h * HC;
    float val;
    if (row < HC)          val = bk[ch + row];
    else if (row < 2 * HC) val = bv[ch + row - HC];
    else                   val = bq[ch + row - 2 * HC];
    bb[idx] = val;
  }
  if (idx < NB * NHEADS * HC * HC) ctx[idx] = 0.f;
  if (idx < NB * NHEADS * HC)      S[idx]   = 0.f;
}

// ---------------- kernel 0b: x [n][c][l] f32 -> xT [n][l][c] fp8 ----------------
__global__ __launch_bounds__(256)
void k_transpose(const float* __restrict__ x, unsigned char* __restrict__ xT) {
  __shared__ float tile[64][65];
  int b = blockIdx.x;
  int ct = b & 3;
  int lt = (b >> 2) & 255;
  int n  = b >> 10;
  int c0 = ct * 64, l0 = lt * 64;
  int t = threadIdx.x;
  int li = t & 63, cr = t >> 6;
  const float* xp = x + (size_t)n * CCH * LSP;
#pragma unroll
  for (int i = 0; i < 16; ++i) {
    int ci = cr * 16 + i;
    tile[ci][li] = xp[(size_t)(c0 + ci) * LSP + l0 + li];
  }
  __syncthreads();
  int cq = t & 15, lg = t >> 4;
  unsigned char* xo = xT + ((size_t)n * LSP + l0) * CCH + c0;
#pragma unroll
  for (int i = 0; i < 4; ++i) {
    int l = lg * 4 + i;
    unsigned pk = cvt4_fp8(tile[cq * 4][l], tile[cq * 4 + 1][l],
                           tile[cq * 4 + 2][l], tile[cq * 4 + 3][l]);
    *(unsigned*)&xo[(size_t)l * CCH + cq * 4] = pk;
  }
}

// ---------------- kernel 1: fused QKV, fp8 staging GEMM, xt double-buffer ----------------
// grid 256: bid = h*32 + (n*4 + q2); 8 h-siblings share bid%8 -> one XCD (x L2-shared).
// 8 waves (2/SIMD) = rh{0,1} x pq{0..3}, wave tile 48 rows x 32 px, fp8 frags (b64).
// rh0 rows 0-47: k(32)+v(0-15) swapped mfma(x,W); rh1: v(16-31) swapped + q(32) normal.
// xt dbuf: stage(t+2) after barrier1 of tile t; counted per-role vmcnt. Strips bf16
// plain [32][136] (pitch-272 natural bank rotation, measured-good in R14).
__global__ __launch_bounds__(512)
void k_fused(const unsigned char* __restrict__ xT,
             const unsigned char* __restrict__ Wb, const float* __restrict__ bb,
             unsigned char* __restrict__ qbuf, float* __restrict__ ctx,
             float* __restrict__ S) {
  __shared__ unsigned char wlds[96 * 256];        // 24 KiB (staged once)
  __shared__ unsigned char xt[2][128 * 256];      // 64 KiB dbuf
  __shared__ unsigned short ekst[2][32][136];     // 17 KiB exp(k) strips, dbuf
  __shared__ unsigned short vst[2][32][136];      // 17 KiB v strips, dbuf

  int bid = (int)blockIdx.x;
  int h = bid >> 5;
  int r5 = bid & 31;
  int n = r5 >> 2, q2 = r5 & 3;
  int l0 = q2 << 12;
  int nh = n * NHEADS + h;
  int tid = threadIdx.x;
  int wid = tid >> 6, lane = tid & 63;
  int r16 = lane & 15, kg = lane >> 4;
  int rh = wid >> 2;          // row half (48 rows)
  int pq = wid & 3;           // px quarter (32 px)

  const unsigned char* xTn = xT + ((size_t)n << 14) * CCH;
  const unsigned char* Wh = Wb + (size_t)h * 96 * CCH;

  // stage 128px x 256ch fp8 tile: 32 x 1KiB pieces, 4/wave; dest linear,
  // source 16B-chunk XOR (3-bit involution, rule 21)
  auto stage_xt = [&](int buf, int tt) {
    int lb = l0 + tt * 128;
#pragma unroll
    for (int i = 0; i < 4; ++i) {
      int p = wid * 4 + i;                   // 0..31
      int px = p * 4 + (lane >> 4);
      int c16 = lane & 15;
      gload_lds16(xTn + ((size_t)(lb + px) << 8) + ((c16 ^ (px & 7)) << 4),
                  &xt[buf][p * 1024]);
    }
  };

  // prologue: W (24 pieces, 3/wave) + tiles 0,1
#pragma unroll
  for (int i = 0; i < 3; ++i) {
    int p = wid * 3 + i;
    int row = p * 4 + (lane >> 4);
    int c16 = lane & 15;
    gload_lds16(Wh + ((size_t)row << 8) + ((c16 ^ (row & 7)) << 4), &wlds[p * 1024]);
  }
  stage_xt(0, 0);
  stage_xt(1, 1);

  float bw[3];
#pragma unroll
  for (int m = 0; m < 3; ++m) bw[m] = bb[h * 96 + rh * 48 + m * 16 + r16];
  float bq[2][4];
#pragma unroll
  for (int m = 0; m < 2; ++m)
#pragma unroll
    for (int r = 0; r < 4; ++r) bq[m][r] = bb[h * 96 + 64 + m * 16 + kg * 4 + r];

  f32x4 actx = {0.f, 0.f, 0.f, 0.f};   // quadrant (ckf=rh, cvf=pq&1), K-half pq>>1
  float sk0 = 0.f, sk1 = 0.f;

  asm volatile("s_waitcnt vmcnt(4)" ::: "memory");   // W + tile0 done; tile1 in flight
  __builtin_amdgcn_sched_barrier(0);
  __builtin_amdgcn_s_barrier();
  __builtin_amdgcn_sched_barrier(0);

  const int base_w = (rh * 48 + r16) * 256;
  const int base_x = (pq * 32 + r16) * 256;
  int kh = pq >> 1, cvf = pq & 1;

  for (int t = 0; t < NT; ++t) {
    int cur = t & 1, sb = t & 1, pb = sb ^ 1;
    // ---- ctx MFMA on previous tile's strips (bf16, one tile behind) ----
    if (t) {
#pragma unroll
      for (int ks = 0; ks < 2; ++ks) {
        int col = kh * 64 + ks * 32 + kg * 8;
        short8 a = *(const short8*)&ekst[pb][rh * 16 + r16][col];
        short8 b = *(const short8*)&vst[pb][cvf * 16 + r16][col];
        actx = __builtin_amdgcn_mfma_f32_16x16x32_bf16(a, b, actx, 0, 0, 0);
      }
    }
    // ---- K-loop: 48 rows x 32 px, fp8 frags (5 b64 reads -> 6 MFMA per kk) ----
    f32x4 acc[3][2];
#pragma unroll
    for (int m = 0; m < 3; ++m) { acc[m][0] = (f32x4){0,0,0,0}; acc[m][1] = (f32x4){0,0,0,0}; }
    const unsigned char* xb = &xt[cur][0];
#pragma unroll
    for (int kk = 0; kk < 8; ++kk) {
      int sw = (((kk * 2 + (kg >> 1)) ^ (r16 & 7)) << 4) + ((kg & 1) << 3);
      ll wf0 = *(const ll*)&wlds[base_w + sw];
      ll wf1 = *(const ll*)&wlds[base_w + 4096 + sw];
      ll wf2 = *(const ll*)&wlds[base_w + 8192 + sw];
      ll xf0 = *(const ll*)&xb[base_x + sw];
      ll xf1 = *(const ll*)&xb[base_x + 4096 + sw];
      if (rh == 0) {
        acc[0][0] = __builtin_amdgcn_mfma_f32_16x16x32_fp8_fp8(xf0, wf0, acc[0][0], 0, 0, 0);
        acc[0][1] = __builtin_amdgcn_mfma_f32_16x16x32_fp8_fp8(xf1, wf0, acc[0][1], 0, 0, 0);
        acc[1][0] = __builtin_amdgcn_mfma_f32_16x16x32_fp8_fp8(xf0, wf1, acc[1][0], 0, 0, 0);
        acc[1][1] = __builtin_amdgcn_mfma_f32_16x16x32_fp8_fp8(xf1, wf1, acc[1][1], 0, 0, 0);
        acc[2][0] = __builtin_amdgcn_mfma_f32_16x16x32_fp8_fp8(xf0, wf2, acc[2][0], 0, 0, 0);
        acc[2][1] = __builtin_amdgcn_mfma_f32_16x16x32_fp8_fp8(xf1, wf2, acc[2][1], 0, 0, 0);
      } else {
        acc[0][0] = __builtin_amdgcn_mfma_f32_16x16x32_fp8_fp8(xf0, wf0, acc[0][0], 0, 0, 0);
        acc[0][1] = __builtin_amdgcn_mfma_f32_16x16x32_fp8_fp8(xf1, wf0, acc[0][1], 0, 0, 0);
        acc[1][0] = __builtin_amdgcn_mfma_f32_16x16x32_fp8_fp8(wf1, xf0, acc[1][0], 0, 0, 0);
        acc[1][1] = __builtin_amdgcn_mfma_f32_16x16x32_fp8_fp8(wf1, xf1, acc[1][1], 0, 0, 0);
        acc[2][0] = __builtin_amdgcn_mfma_f32_16x16x32_fp8_fp8(wf2, xf0, acc[2][0], 0, 0, 0);
        acc[2][1] = __builtin_amdgcn_mfma_f32_16x16x32_fp8_fp8(wf2, xf1, acc[2][1], 0, 0, 0);
      }
    }
    __builtin_amdgcn_s_barrier();          // barrier1: all waves done reading xt[cur]
    if (t + 2 < NT) stage_xt(cur, t + 2);  // refill freed buffer; full-tile DMA window

    // ---- epilogue (wave-local); acc * 1/64 undoes W pre-scale ----
    if (rh == 0) {
#pragma unroll
      for (int nf = 0; nf < 2; ++nf) {
        int col = pq * 32 + nf * 16 + kg * 4;
#pragma unroll
        for (int m = 0; m < 2; ++m) {       // k rows -> exp strips + S
          float e0 = __expf(acc[m][nf][0] * WSC + bw[m]);
          float e1 = __expf(acc[m][nf][1] * WSC + bw[m]);
          float e2 = __expf(acc[m][nf][2] * WSC + bw[m]);
          float e3 = __expf(acc[m][nf][3] * WSC + bw[m]);
          if (m == 0) sk0 += e0 + e1 + e2 + e3; else sk1 += e0 + e1 + e2 + e3;
          uint2 u = {cvt_pk_bf16(e0, e1), cvt_pk_bf16(e2, e3)};
          *(uint2*)&ekst[sb][m * 16 + r16][col] = u;
        }
        {                                    // v rows 0-15
          float v0 = acc[2][nf][0] * WSC + bw[2], v1 = acc[2][nf][1] * WSC + bw[2];
          float v2 = acc[2][nf][2] * WSC + bw[2], v3 = acc[2][nf][3] * WSC + bw[2];
          uint2 u = {cvt_pk_bf16(v0, v1), cvt_pk_bf16(v2, v3)};
          *(uint2*)&vst[sb][r16][col] = u;
        }
      }
    } else {
#pragma unroll
      for (int nf = 0; nf < 2; ++nf) {
        int col = pq * 32 + nf * 16 + kg * 4;
        {                                    // v rows 16-31
          float v0 = acc[0][nf][0] * WSC + bw[0], v1 = acc[0][nf][1] * WSC + bw[0];
          float v2 = acc[0][nf][2] * WSC + bw[0], v3 = acc[0][nf][3] * WSC + bw[0];
          uint2 u = {cvt_pk_bf16(v0, v1), cvt_pk_bf16(v2, v3)};
          *(uint2*)&vst[sb][16 + r16][col] = u;
        }
        // q: softmax over 32 ck, wholly in-wave (8 in-lane + shfl 16,32); store fp8
        float ea[4], eb[4];
        float s = 0.f;
#pragma unroll
        for (int r = 0; r < 4; ++r) {
          ea[r] = __expf(acc[1][nf][r] * WSC + bq[0][r]);
          eb[r] = __expf(acc[2][nf][r] * WSC + bq[1][r]);
          s += ea[r] + eb[r];
        }
        s += __shfl_xor(s, 16);
        s += __shfl_xor(s, 32);
        float inv = 1.f / s;
        int l = l0 + t * 128 + pq * 32 + nf * 16 + r16;
        unsigned char* qb = qbuf + (((size_t)nh * LSP + l) << 5);
        unsigned u0 = cvt4_fp8(ea[0] * inv, ea[1] * inv, ea[2] * inv, ea[3] * inv);
        unsigned u1 = cvt4_fp8(eb[0] * inv, eb[1] * inv, eb[2] * inv, eb[3] * inv);
        *(unsigned*)&qb[kg * 4]      = u0;
        *(unsigned*)&qb[16 + kg * 4] = u1;
      }
    }
    // barrier2: strips visible; next tile's buffer staged (counted, per-role)
    asm volatile("s_waitcnt lgkmcnt(0)" ::: "memory");
    __builtin_amdgcn_sched_barrier(0);
    if (t < NT - 2) {
      if (rh == 0) { asm volatile("s_waitcnt vmcnt(4)" ::: "memory"); }
      else         { asm volatile("s_waitcnt vmcnt(8)" ::: "memory"); }
    } else if (t == NT - 2) {
      if (rh == 0) { asm volatile("s_waitcnt vmcnt(0)" ::: "memory"); }
      else         { asm volatile("s_waitcnt vmcnt(4)" ::: "memory"); }
    }
    __builtin_amdgcn_sched_barrier(0);
    __builtin_amdgcn_s_barrier();
    __builtin_amdgcn_sched_barrier(0);
  }

  // final ctx on last tile's strips
#pragma unroll
  for (int ks = 0; ks < 2; ++ks) {
    int col = kh * 64 + ks * 32 + kg * 8;
    short8 a = *(const short8*)&ekst[(NT - 1) & 1][rh * 16 + r16][col];
    short8 b = *(const short8*)&vst[(NT - 1) & 1][cvf * 16 + r16][col];
    actx = __builtin_amdgcn_mfma_f32_16x16x32_bf16(a, b, actx, 0, 0, 0);
  }
  // flush: ctx quadrant + S rows
  float* cp = ctx + ((size_t)nh << 10);
#pragma unroll
  for (int r = 0; r < 4; ++r)
    atomicAdd(&cp[(rh * 16 + kg * 4 + r) * HC + cvf * 16 + r16], actx[r]);
  if (rh == 0) {
    float s0 = sk0, s1 = sk1;
    s0 += __shfl_xor(s0, 16); s0 += __shfl_xor(s0, 32);
    s1 += __shfl_xor(s1, 16); s1 += __shfl_xor(s1, 32);
    if (kg == 0) {
      atomicAdd(&S[nh * HC + r16], s0);
      atomicAdd(&S[nh * HC + 16 + r16], s1);
    }
  }
}

// ---------------- kernel 2: ctx/S, transpose, -> fp8 ----------------
__global__ void k_norm(const float* __restrict__ ctx, const float* __restrict__ S,
                       unsigned char* __restrict__ ctxT) {
  int idx = blockIdx.x * 256 + threadIdx.x;  // 65536 = [n][h][ck][cv]
  int cv = idx & 31, ck = (idx >> 5) & 31, nh = idx >> 10;
  float v = ctx[idx] / S[(nh << 5) + ck];
  ctxT[(nh << 10) + (cv << 5) + ck] = f2fp8(v);
}

// ---------------- kernel 3: att = ctxT (fp8) x q_soft (fp8) + residual ----------------
__global__ __launch_bounds__(256)
void k_att(const float* __restrict__ x, const unsigned char* __restrict__ qbuf,
           const unsigned char* __restrict__ ctxT, float* __restrict__ out) {
  int b = blockIdx.x;
  int lc = b & 63;
  int nh = b >> 6;
  int h = nh & 7, n = nh >> 3;
  int tid = threadIdx.x, wid = tid >> 6, lane = tid & 63;
  int r16 = lane & 15, kg = lane >> 4;
  int lw = lc * 256 + wid * 64;

  const unsigned char* cp = ctxT + ((size_t)nh << 10);
  ll a0 = *(const ll*)&cp[(r16 << 5) + kg * 8];          // A[cv][ck], cv 0-15
  ll a1 = *(const ll*)&cp[((16 + r16) << 5) + kg * 8];   // cv 16-31
  const unsigned char* qb = qbuf + (((size_t)nh * LSP) << 5);
  const float* xp = x   + ((size_t)n * CCH + (size_t)h * HC) * LSP;
  float*       op = out + ((size_t)n * CCH + (size_t)h * HC) * LSP;

#pragma unroll
  for (int t = 0; t < 4; ++t) {
    int l = lw + t * 16;
    ll bq = *(const ll*)&qb[((size_t)(l + r16) << 5) + kg * 8];  // softmaxed q [l][ck] fp8
    f32x4 d0 = {0, 0, 0, 0}, d1 = {0, 0, 0, 0};
    d0 = __builtin_amdgcn_mfma_f32_16x16x32_fp8_fp8(a0, bq, d0, 0, 0, 0);
    d1 = __builtin_amdgcn_mfma_f32_16x16x32_fp8_fp8(a1, bq, d1, 0, 0, 0);
#pragma unroll
    for (int r = 0; r < 4; ++r) {
      int cv = kg * 4 + r;
      int li = l + r16;
      op[(size_t)cv * LSP + li]        = d0[r] + xp[(size_t)cv * LSP + li];
      op[(size_t)(cv + 16) * LSP + li] = d1[r] + xp[(size_t)(cv + 16) * LSP + li];
    }
  }
}

extern "C" void kernel_launch(void* const* d_in, const int* in_sizes, int n_in,
                              void* d_out, int out_size, void* d_ws, size_t ws_size,
                              hipStream_t stream) {
  (void)in_sizes; (void)n_in; (void)out_size; (void)ws_size;
  const float* x  = (const float*)d_in[0];
  const float* Wk = (const float*)d_in[1];
  const float* bk = (const float*)d_in[2];
  const float* Wq = (const float*)d_in[3];
  const float* bq = (const float*)d_in[4];
  const float* Wv = (const float*)d_in[5];
  const float* bv = (const float*)d_in[6];
  float* out = (float*)d_out;

  char* ws = (char*)d_ws;
  unsigned char*  Wb   = (unsigned char*)(ws + 0);           //    196608 (fp8, x64-scaled)
  float*          bbp  = (float*)(ws + 196608);              //      3072
  float*          ctx  = (float*)(ws + 199680);              //    262144
  unsigned char*  ctxT = (unsigned char*)(ws + 461824);      //     32768 (fp8)
  float*          S    = (float*)(ws + 494592);              //      8192
  unsigned char*  qbuf = (unsigned char*)(ws + 502784);      //  33554432 (fp8)
  unsigned char*  xT   = (unsigned char*)(ws + 34057216);    //  33554432 (fp8) -> 67611648

  k_prep<<<768, 256, 0, stream>>>(Wk, bk, Wq, bq, Wv, bv, Wb, bbp, ctx, S);
  k_transpose<<<NB * 256 * 4, 256, 0, stream>>>(x, xT);
  k_fused<<<256, 512, 0, stream>>>(xT, Wb, bbp, qbuf, ctx, S);
  k_norm<<<256, 256, 0, stream>>>(ctx, S, ctxT);
  k_att<<<NB * NHEADS * 64, 256, 0, stream>>>(x, qbuf, ctxT, out);
}

// Round 17
// 170.341 us; speedup vs baseline: 1.8178x; 1.0964x over previous
//
#include <hip/hip_runtime.h>

// EfficientAttention: N=8, C=256, H=W=128 (L=16384), HEADS=8, hc=32
// out = x + att,  att[n,h,cv,l] = sum_ck (ctx[ck,cv]/S[ck]) * softmax_ck(q)[ck,l]
// ctx[ck,cv] = sum_l exp(k[ck,l]) * v[cv,l],  S[ck] = sum_l exp(k[ck,l])
//
// R17 = R16 with k_fused split into 2 independent blocks/CU: 64-px tiles,
// 4 waves (256 thr), LDS 74KB -> 2 blocks co-resident with decoupled barrier
// domains (lockstep was the residual stall: all pipes ~25% busy at R16).
// Same wave tile (48x32), fp8 staging, strip layout, counted vmcnt.

typedef __attribute__((ext_vector_type(8))) short short8;
typedef __attribute__((ext_vector_type(4))) float f32x4;
typedef long long ll;

#define NB     8
#define CCH    256
#define LSP    16384
#define NHEADS 8
#define HC     32
#define NT     32     // 64-px tiles per block (2048-px range)
#define WSC    0.015625f   // 1/64: undo W pre-scale

__device__ __forceinline__ unsigned short f2bf(float f) {
  union { float f; unsigned u; } v; v.f = f;
  unsigned r = v.u + 0x7fffu + ((v.u >> 16) & 1u);   // RNE
  return (unsigned short)(r >> 16);
}
__device__ __forceinline__ unsigned cvt_pk_bf16(float lo, float hi) {
  unsigned r;
  asm("v_cvt_pk_bf16_f32 %0, %1, %2" : "=v"(r) : "v"(lo), "v"(hi));
  return r;
}
// 4 floats -> 4 fp8 e4m3 packed in a u32 (HW cvt, RNE)
__device__ __forceinline__ unsigned cvt4_fp8(float a, float b, float c, float d) {
  unsigned r;
  asm("v_cvt_pk_fp8_f32 %0, %1, %2\n\t"
      "v_cvt_pk_fp8_f32 %0, %3, %4 op_sel:[0,0,1]"
      : "=v"(r) : "v"(a), "v"(b), "v"(c), "v"(d));
  return r;
}
// float -> fp8 e4m3fn (software, for once-only prep kernels)
__device__ __forceinline__ unsigned char f2fp8(float f) {
  union { float f; unsigned u; } v; v.f = f;
  unsigned s = (v.u >> 24) & 0x80u;
  unsigned x = v.u & 0x7FFFFFFFu;
  if (x < 0x3C800000u) {
    float a = fabsf(f);
    int q = (int)rintf(a * 512.f);
    return (unsigned char)(s | (unsigned)q);
  }
  unsigned r = x + 0xFFFFFu + ((x >> 20) & 1u);
  unsigned e = r >> 23;
  unsigned m = (r >> 20) & 7u;
  int fe = (int)e - 120;
  if (fe > 15 || (fe == 15 && m == 7)) return (unsigned char)(s | 0x7Eu);
  return (unsigned char)(s | ((unsigned)fe << 3) | m);
}
__device__ __forceinline__ void gload_lds16(const unsigned char* g, unsigned char* l) {
  __builtin_amdgcn_global_load_lds(
      (const __attribute__((address_space(1))) unsigned int*)g,
      (__attribute__((address_space(3))) unsigned int*)l, 16, 0, 0);
}

// ---------------- kernel 0: weights -> fp8 (x64 pre-scale) head-grouped [k32|v32|q32] ------
__global__ void k_prep(const float* __restrict__ Wk, const float* __restrict__ bk,
                       const float* __restrict__ Wq, const float* __restrict__ bq,
                       const float* __restrict__ Wv, const float* __restrict__ bv,
                       unsigned char* __restrict__ Wb, float* __restrict__ bb,
                       float* __restrict__ ctx, float* __restrict__ S) {
  int idx = blockIdx.x * 256 + threadIdx.x;
  if (idx < NHEADS * 96 * CCH) {
    int c = idx & (CCH - 1);
    int row = (idx >> 8) % 96;
    int h = idx / (96 * CCH);
    int ch = h * HC;
    float val;
    if (row < HC)          val = Wk[(ch + row) * CCH + c];
    else if (row < 2 * HC) val = Wv[(ch + row - HC) * CCH + c];
    else                   val = Wq[(ch + row - 2 * HC) * CCH + c];
    Wb[idx] = f2fp8(val * 64.f);
  }
  if (idx < NHEADS * 96) {
    int row = idx % 96, h = idx / 96, ch = h * HC;
    float val;
    if (row < HC)          val = bk[ch + row];
    else if (row < 2 * HC) val = bv[ch + row - HC];
    else                   val = bq[ch + row - 2 * HC];
    bb[idx] = val;
  }
  if (idx < NB * NHEADS * HC * HC) ctx[idx] = 0.f;
  if (idx < NB * NHEADS * HC)      S[idx]   = 0.f;
}

// ---------------- kernel 0b: x [n][c][l] f32 -> xT [n][l][c] fp8 ----------------
__global__ __launch_bounds__(256)
void k_transpose(const float* __restrict__ x, unsigned char* __restrict__ xT) {
  __shared__ float tile[64][65];
  int b = blockIdx.x;
  int ct = b & 3;
  int lt = (b >> 2) & 255;
  int n  = b >> 10;
  int c0 = ct * 64, l0 = lt * 64;
  int t = threadIdx.x;
  int li = t & 63, cr = t >> 6;
  const float* xp = x + (size_t)n * CCH * LSP;
#pragma unroll
  for (int i = 0; i < 16; ++i) {
    int ci = cr * 16 + i;
    tile[ci][li] = xp[(size_t)(c0 + ci) * LSP + l0 + li];
  }
  __syncthreads();
  int cq = t & 15, lg = t >> 4;
  unsigned char* xo = xT + ((size_t)n * LSP + l0) * CCH + c0;
#pragma unroll
  for (int i = 0; i < 4; ++i) {
    int l = lg * 4 + i;
    unsigned pk = cvt4_fp8(tile[cq * 4][l], tile[cq * 4 + 1][l],
                           tile[cq * 4 + 2][l], tile[cq * 4 + 3][l]);
    *(unsigned*)&xo[(size_t)l * CCH + cq * 4] = pk;
  }
}

// ---------------- kernel 1: fused QKV, 2 blocks/CU, 4 waves, 64-px tiles ----------------
// grid 512 = 8h x 8n x 8g; bid = h*64 + n*8 + g -> h-siblings differ by 64 (mult of 8)
// -> same XCD (x L2-shared). 4 waves = rh{0,1} x pq{0,1}; wave tile 48 rows x 32 px.
// rh0 rows 0-47: k(32)+v(0-15) swapped mfma(x,W); rh1: v(16-31) swapped + q(32) normal.
// LDS 74KB -> 2 independent blocks/CU (decoupled barriers). fp8 frags, counted vmcnt.
__global__ __launch_bounds__(256)
void k_fused(const unsigned char* __restrict__ xT,
             const unsigned char* __restrict__ Wb, const float* __restrict__ bb,
             unsigned char* __restrict__ qbuf, float* __restrict__ ctx,
             float* __restrict__ S) {
  __shared__ unsigned char wlds[96 * 256];        // 24 KiB (staged once)
  __shared__ unsigned char xt[2][64 * 256];       // 32 KiB dbuf
  __shared__ unsigned short ekst[2][32][72];      // 9 KiB exp(k) strips, dbuf
  __shared__ unsigned short vst[2][32][72];       // 9 KiB v strips, dbuf

  int bid = (int)blockIdx.x;
  int h = bid >> 6;
  int r6 = bid & 63;
  int n = r6 >> 3, g = r6 & 7;
  int l0 = g << 11;                  // 2048-px range
  int nh = n * NHEADS + h;
  int tid = threadIdx.x;
  int wid = tid >> 6, lane = tid & 63;
  int r16 = lane & 15, kg = lane >> 4;
  int rh = wid >> 1;          // row half (48 rows)
  int pq = wid & 1;           // px half (32 px)

  const unsigned char* xTn = xT + ((size_t)n << 14) * CCH;
  const unsigned char* Wh = Wb + (size_t)h * 96 * CCH;

  // stage 64px x 256ch fp8 tile: 16 x 1KiB pieces, 4/wave; dest linear,
  // source 16B-chunk XOR (3-bit involution, rule 21)
  auto stage_xt = [&](int buf, int tt) {
    int lb = l0 + tt * 64;
#pragma unroll
    for (int i = 0; i < 4; ++i) {
      int p = wid * 4 + i;                   // 0..15
      int px = p * 4 + (lane >> 4);
      int c16 = lane & 15;
      gload_lds16(xTn + ((size_t)(lb + px) << 8) + ((c16 ^ (px & 7)) << 4),
                  &xt[buf][p * 1024]);
    }
  };

  // prologue: W (24 pieces, 6/wave) + tiles 0,1
#pragma unroll
  for (int i = 0; i < 6; ++i) {
    int p = wid * 6 + i;
    int row = p * 4 + (lane >> 4);
    int c16 = lane & 15;
    gload_lds16(Wh + ((size_t)row << 8) + ((c16 ^ (row & 7)) << 4), &wlds[p * 1024]);
  }
  stage_xt(0, 0);
  stage_xt(1, 1);

  float bw[3];
#pragma unroll
  for (int m = 0; m < 3; ++m) bw[m] = bb[h * 96 + rh * 48 + m * 16 + r16];
  float bq[2][4];
#pragma unroll
  for (int m = 0; m < 2; ++m)
#pragma unroll
    for (int r = 0; r < 4; ++r) bq[m][r] = bb[h * 96 + 64 + m * 16 + kg * 4 + r];

  f32x4 actx = {0.f, 0.f, 0.f, 0.f};   // quadrant (ckf=rh, cvf=pq), K = full 64 px
  float sk0 = 0.f, sk1 = 0.f;

  asm volatile("s_waitcnt vmcnt(4)" ::: "memory");   // W + tile0 done; tile1 in flight
  __builtin_amdgcn_sched_barrier(0);
  __builtin_amdgcn_s_barrier();
  __builtin_amdgcn_sched_barrier(0);

  const int base_w = (rh * 48 + r16) * 256;
  const int base_x = (pq * 32 + r16) * 256;

  for (int t = 0; t < NT; ++t) {
    int cur = t & 1, sb = t & 1, pb = sb ^ 1;
    // ---- ctx MFMA on previous tile's strips (bf16, one tile behind) ----
    if (t) {
#pragma unroll
      for (int ks = 0; ks < 2; ++ks) {
        int col = ks * 32 + kg * 8;
        short8 a = *(const short8*)&ekst[pb][rh * 16 + r16][col];
        short8 b = *(const short8*)&vst[pb][pq * 16 + r16][col];
        actx = __builtin_amdgcn_mfma_f32_16x16x32_bf16(a, b, actx, 0, 0, 0);
      }
    }
    // ---- K-loop: 48 rows x 32 px, fp8 frags (5 b64 reads -> 6 MFMA per kk) ----
    f32x4 acc[3][2];
#pragma unroll
    for (int m = 0; m < 3; ++m) { acc[m][0] = (f32x4){0,0,0,0}; acc[m][1] = (f32x4){0,0,0,0}; }
    const unsigned char* xb = &xt[cur][0];
#pragma unroll
    for (int kk = 0; kk < 8; ++kk) {
      int sw = (((kk * 2 + (kg >> 1)) ^ (r16 & 7)) << 4) + ((kg & 1) << 3);
      ll wf0 = *(const ll*)&wlds[base_w + sw];
      ll wf1 = *(const ll*)&wlds[base_w + 4096 + sw];
      ll wf2 = *(const ll*)&wlds[base_w + 8192 + sw];
      ll xf0 = *(const ll*)&xb[base_x + sw];
      ll xf1 = *(const ll*)&xb[base_x + 4096 + sw];
      if (rh == 0) {
        acc[0][0] = __builtin_amdgcn_mfma_f32_16x16x32_fp8_fp8(xf0, wf0, acc[0][0], 0, 0, 0);
        acc[0][1] = __builtin_amdgcn_mfma_f32_16x16x32_fp8_fp8(xf1, wf0, acc[0][1], 0, 0, 0);
        acc[1][0] = __builtin_amdgcn_mfma_f32_16x16x32_fp8_fp8(xf0, wf1, acc[1][0], 0, 0, 0);
        acc[1][1] = __builtin_amdgcn_mfma_f32_16x16x32_fp8_fp8(xf1, wf1, acc[1][1], 0, 0, 0);
        acc[2][0] = __builtin_amdgcn_mfma_f32_16x16x32_fp8_fp8(xf0, wf2, acc[2][0], 0, 0, 0);
        acc[2][1] = __builtin_amdgcn_mfma_f32_16x16x32_fp8_fp8(xf1, wf2, acc[2][1], 0, 0, 0);
      } else {
        acc[0][0] = __builtin_amdgcn_mfma_f32_16x16x32_fp8_fp8(xf0, wf0, acc[0][0], 0, 0, 0);
        acc[0][1] = __builtin_amdgcn_mfma_f32_16x16x32_fp8_fp8(xf1, wf0, acc[0][1], 0, 0, 0);
        acc[1][0] = __builtin_amdgcn_mfma_f32_16x16x32_fp8_fp8(wf1, xf0, acc[1][0], 0, 0, 0);
        acc[1][1] = __builtin_amdgcn_mfma_f32_16x16x32_fp8_fp8(wf1, xf1, acc[1][1], 0, 0, 0);
        acc[2][0] = __builtin_amdgcn_mfma_f32_16x16x32_fp8_fp8(wf2, xf0, acc[2][0], 0, 0, 0);
        acc[2][1] = __builtin_amdgcn_mfma_f32_16x16x32_fp8_fp8(wf2, xf1, acc[2][1], 0, 0, 0);
      }
    }
    __builtin_amdgcn_s_barrier();          // barrier1: all waves done reading xt[cur]
    if (t + 2 < NT) stage_xt(cur, t + 2);  // refill freed buffer; full-tile DMA window

    // ---- epilogue (wave-local); acc * 1/64 undoes W pre-scale ----
    if (rh == 0) {
#pragma unroll
      for (int nf = 0; nf < 2; ++nf) {
        int col = pq * 32 + nf * 16 + kg * 4;
#pragma unroll
        for (int m = 0; m < 2; ++m) {       // k rows -> exp strips + S
          float e0 = __expf(acc[m][nf][0] * WSC + bw[m]);
          float e1 = __expf(acc[m][nf][1] * WSC + bw[m]);
          float e2 = __expf(acc[m][nf][2] * WSC + bw[m]);
          float e3 = __expf(acc[m][nf][3] * WSC + bw[m]);
          if (m == 0) sk0 += e0 + e1 + e2 + e3; else sk1 += e0 + e1 + e2 + e3;
          uint2 u = {cvt_pk_bf16(e0, e1), cvt_pk_bf16(e2, e3)};
          *(uint2*)&ekst[sb][m * 16 + r16][col] = u;
        }
        {                                    // v rows 0-15
          float v0 = acc[2][nf][0] * WSC + bw[2], v1 = acc[2][nf][1] * WSC + bw[2];
          float v2 = acc[2][nf][2] * WSC + bw[2], v3 = acc[2][nf][3] * WSC + bw[2];
          uint2 u = {cvt_pk_bf16(v0, v1), cvt_pk_bf16(v2, v3)};
          *(uint2*)&vst[sb][r16][col] = u;
        }
      }
    } else {
#pragma unroll
      for (int nf = 0; nf < 2; ++nf) {
        int col = pq * 32 + nf * 16 + kg * 4;
        {                                    // v rows 16-31
          float v0 = acc[0][nf][0] * WSC + bw[0], v1 = acc[0][nf][1] * WSC + bw[0];
          float v2 = acc[0][nf][2] * WSC + bw[0], v3 = acc[0][nf][3] * WSC + bw[0];
          uint2 u = {cvt_pk_bf16(v0, v1), cvt_pk_bf16(v2, v3)};
          *(uint2*)&vst[sb][16 + r16][col] = u;
        }
        // q: softmax over 32 ck, wholly in-wave (8 in-lane + shfl 16,32); store fp8
        float ea[4], eb[4];
        float s = 0.f;
#pragma unroll
        for (int r = 0; r < 4; ++r) {
          ea[r] = __expf(acc[1][nf][r] * WSC + bq[0][r]);
          eb[r] = __expf(acc[2][nf][r] * WSC + bq[1][r]);
          s += ea[r] + eb[r];
        }
        s += __shfl_xor(s, 16);
        s += __shfl_xor(s, 32);
        float inv = 1.f / s;
        int l = l0 + t * 64 + pq * 32 + nf * 16 + r16;
        unsigned char* qb = qbuf + (((size_t)nh * LSP + l) << 5);
        unsigned u0 = cvt4_fp8(ea[0] * inv, ea[1] * inv, ea[2] * inv, ea[3] * inv);
        unsigned u1 = cvt4_fp8(eb[0] * inv, eb[1] * inv, eb[2] * inv, eb[3] * inv);
        *(unsigned*)&qb[kg * 4]      = u0;
        *(unsigned*)&qb[16 + kg * 4] = u1;
      }
    }
    // barrier2: strips visible; next tile's buffer staged (counted, per-role)
    asm volatile("s_waitcnt lgkmcnt(0)" ::: "memory");
    __builtin_amdgcn_sched_barrier(0);
    if (t < NT - 2) {
      if (rh == 0) { asm volatile("s_waitcnt vmcnt(4)" ::: "memory"); }
      else         { asm volatile("s_waitcnt vmcnt(8)" ::: "memory"); }
    } else if (t == NT - 2) {
      if (rh == 0) { asm volatile("s_waitcnt vmcnt(0)" ::: "memory"); }
      else         { asm volatile("s_waitcnt vmcnt(4)" ::: "memory"); }
    }
    __builtin_amdgcn_sched_barrier(0);
    __builtin_amdgcn_s_barrier();
    __builtin_amdgcn_sched_barrier(0);
  }

  // final ctx on last tile's strips
#pragma unroll
  for (int ks = 0; ks < 2; ++ks) {
    int col = ks * 32 + kg * 8;
    short8 a = *(const short8*)&ekst[(NT - 1) & 1][rh * 16 + r16][col];
    short8 b = *(const short8*)&vst[(NT - 1) & 1][pq * 16 + r16][col];
    actx = __builtin_amdgcn_mfma_f32_16x16x32_bf16(a, b, actx, 0, 0, 0);
  }
  // flush: ctx quadrant + S rows
  float* cp = ctx + ((size_t)nh << 10);
#pragma unroll
  for (int r = 0; r < 4; ++r)
    atomicAdd(&cp[(rh * 16 + kg * 4 + r) * HC + pq * 16 + r16], actx[r]);
  if (rh == 0) {
    float s0 = sk0, s1 = sk1;
    s0 += __shfl_xor(s0, 16); s0 += __shfl_xor(s0, 32);
    s1 += __shfl_xor(s1, 16); s1 += __shfl_xor(s1, 32);
    if (kg == 0) {
      atomicAdd(&S[nh * HC + r16], s0);
      atomicAdd(&S[nh * HC + 16 + r16], s1);
    }
  }
}

// ---------------- kernel 2: ctx/S, transpose, -> fp8 ----------------
__global__ void k_norm(const float* __restrict__ ctx, const float* __restrict__ S,
                       unsigned char* __restrict__ ctxT) {
  int idx = blockIdx.x * 256 + threadIdx.x;  // 65536 = [n][h][ck][cv]
  int cv = idx & 31, ck = (idx >> 5) & 31, nh = idx >> 10;
  float v = ctx[idx] / S[(nh << 5) + ck];
  ctxT[(nh << 10) + (cv << 5) + ck] = f2fp8(v);
}

// ---------------- kernel 3: att = ctxT (fp8) x q_soft (fp8) + residual ----------------
__global__ __launch_bounds__(256)
void k_att(const float* __restrict__ x, const unsigned char* __restrict__ qbuf,
           const unsigned char* __restrict__ ctxT, float* __restrict__ out) {
  int b = blockIdx.x;
  int lc = b & 63;
  int nh = b >> 6;
  int h = nh & 7, n = nh >> 3;
  int tid = threadIdx.x, wid = tid >> 6, lane = tid & 63;
  int r16 = lane & 15, kg = lane >> 4;
  int lw = lc * 256 + wid * 64;

  const unsigned char* cp = ctxT + ((size_t)nh << 10);
  ll a0 = *(const ll*)&cp[(r16 << 5) + kg * 8];          // A[cv][ck], cv 0-15
  ll a1 = *(const ll*)&cp[((16 + r16) << 5) + kg * 8];   // cv 16-31
  const unsigned char* qb = qbuf + (((size_t)nh * LSP) << 5);
  const float* xp = x   + ((size_t)n * CCH + (size_t)h * HC) * LSP;
  float*       op = out + ((size_t)n * CCH + (size_t)h * HC) * LSP;

#pragma unroll
  for (int t = 0; t < 4; ++t) {
    int l = lw + t * 16;
    ll bq = *(const ll*)&qb[((size_t)(l + r16) << 5) + kg * 8];  // softmaxed q [l][ck] fp8
    f32x4 d0 = {0, 0, 0, 0}, d1 = {0, 0, 0, 0};
    d0 = __builtin_amdgcn_mfma_f32_16x16x32_fp8_fp8(a0, bq, d0, 0, 0, 0);
    d1 = __builtin_amdgcn_mfma_f32_16x16x32_fp8_fp8(a1, bq, d1, 0, 0, 0);
#pragma unroll
    for (int r = 0; r < 4; ++r) {
      int cv = kg * 4 + r;
      int li = l + r16;
      op[(size_t)cv * LSP + li]        = d0[r] + xp[(size_t)cv * LSP + li];
      op[(size_t)(cv + 16) * LSP + li] = d1[r] + xp[(size_t)(cv + 16) * LSP + li];
    }
  }
}

extern "C" void kernel_launch(void* const* d_in, const int* in_sizes, int n_in,
                              void* d_out, int out_size, void* d_ws, size_t ws_size,
                              hipStream_t stream) {
  (void)in_sizes; (void)n_in; (void)out_size; (void)ws_size;
  const float* x  = (const float*)d_in[0];
  const float* Wk = (const float*)d_in[1];
  const float* bk = (const float*)d_in[2];
  const float* Wq = (const float*)d_in[3];
  const float* bq = (const float*)d_in[4];
  const float* Wv = (const float*)d_in[5];
  const float* bv = (const float*)d_in[6];
  float* out = (float*)d_out;

  char* ws = (char*)d_ws;
  unsigned char*  Wb   = (unsigned char*)(ws + 0);           //    196608 (fp8, x64-scaled)
  float*          bbp  = (float*)(ws + 196608);              //      3072
  float*          ctx  = (float*)(ws + 199680);              //    262144
  unsigned char*  ctxT = (unsigned char*)(ws + 461824);      //     32768 (fp8)
  float*          S    = (float*)(ws + 494592);              //      8192
  unsigned char*  qbuf = (unsigned char*)(ws + 502784);      //  33554432 (fp8)
  unsigned char*  xT   = (unsigned char*)(ws + 34057216);    //  33554432 (fp8) -> 67611648

  k_prep<<<768, 256, 0, stream>>>(Wk, bk, Wq, bq, Wv, bv, Wb, bbp, ctx, S);
  k_transpose<<<NB * 256 * 4, 256, 0, stream>>>(x, xT);
  k_fused<<<512, 256, 0, stream>>>(xT, Wb, bbp, qbuf, ctx, S);
  k_norm<<<256, 256, 0, stream>>>(ctx, S, ctxT);
  k_att<<<NB * NHEADS * 64, 256, 0, stream>>>(x, qbuf, ctxT, out);
}

// Round 18
// 166.137 us; speedup vs baseline: 1.8638x; 1.0253x over previous
//
#include <hip/hip_runtime.h>

// EfficientAttention: N=8, C=256, H=W=128 (L=16384), HEADS=8, hc=32
// out = x + att,  att[n,h,cv,l] = sum_ck (ctx[ck,cv]/S[ck]) * softmax_ck(q)[ck,l]
// ctx[ck,cv] = sum_l exp(k[ck,l]) * v[cv,l],  S[ck] = sum_l exp(k[ck,l])
//
// R18 = R17 + W fragments held in registers (24 b64 = 48 VGPR/wave, loaded from
// LDS once after staging): K-loop LDS reads drop 40 -> 16 b64 per tile per wave.
// R17 analysis: pipes serialized within a block (2.97k cyc/block-tile = serial sum);
// the 24 W-frag re-reads x32 tiles were 60% of the K-loop LDS stream.

typedef __attribute__((ext_vector_type(8))) short short8;
typedef __attribute__((ext_vector_type(4))) float f32x4;
typedef long long ll;

#define NB     8
#define CCH    256
#define LSP    16384
#define NHEADS 8
#define HC     32
#define NT     32     // 64-px tiles per block (2048-px range)
#define WSC    0.015625f   // 1/64: undo W pre-scale

__device__ __forceinline__ unsigned short f2bf(float f) {
  union { float f; unsigned u; } v; v.f = f;
  unsigned r = v.u + 0x7fffu + ((v.u >> 16) & 1u);   // RNE
  return (unsigned short)(r >> 16);
}
__device__ __forceinline__ unsigned cvt_pk_bf16(float lo, float hi) {
  unsigned r;
  asm("v_cvt_pk_bf16_f32 %0, %1, %2" : "=v"(r) : "v"(lo), "v"(hi));
  return r;
}
// 4 floats -> 4 fp8 e4m3 packed in a u32 (HW cvt, RNE)
__device__ __forceinline__ unsigned cvt4_fp8(float a, float b, float c, float d) {
  unsigned r;
  asm("v_cvt_pk_fp8_f32 %0, %1, %2\n\t"
      "v_cvt_pk_fp8_f32 %0, %3, %4 op_sel:[0,0,1]"
      : "=v"(r) : "v"(a), "v"(b), "v"(c), "v"(d));
  return r;
}
// float -> fp8 e4m3fn (software, for once-only prep kernels)
__device__ __forceinline__ unsigned char f2fp8(float f) {
  union { float f; unsigned u; } v; v.f = f;
  unsigned s = (v.u >> 24) & 0x80u;
  unsigned x = v.u & 0x7FFFFFFFu;
  if (x < 0x3C800000u) {
    float a = fabsf(f);
    int q = (int)rintf(a * 512.f);
    return (unsigned char)(s | (unsigned)q);
  }
  unsigned r = x + 0xFFFFFu + ((x >> 20) & 1u);
  unsigned e = r >> 23;
  unsigned m = (r >> 20) & 7u;
  int fe = (int)e - 120;
  if (fe > 15 || (fe == 15 && m == 7)) return (unsigned char)(s | 0x7Eu);
  return (unsigned char)(s | ((unsigned)fe << 3) | m);
}
__device__ __forceinline__ void gload_lds16(const unsigned char* g, unsigned char* l) {
  __builtin_amdgcn_global_load_lds(
      (const __attribute__((address_space(1))) unsigned int*)g,
      (__attribute__((address_space(3))) unsigned int*)l, 16, 0, 0);
}

// ---------------- kernel 0: weights -> fp8 (x64 pre-scale) head-grouped [k32|v32|q32] ------
__global__ void k_prep(const float* __restrict__ Wk, const float* __restrict__ bk,
                       const float* __restrict__ Wq, const float* __restrict__ bq,
                       const float* __restrict__ Wv, const float* __restrict__ bv,
                       unsigned char* __restrict__ Wb, float* __restrict__ bb,
                       float* __restrict__ ctx, float* __restrict__ S) {
  int idx = blockIdx.x * 256 + threadIdx.x;
  if (idx < NHEADS * 96 * CCH) {
    int c = idx & (CCH - 1);
    int row = (idx >> 8) % 96;
    int h = idx / (96 * CCH);
    int ch = h * HC;
    float val;
    if (row < HC)          val = Wk[(ch + row) * CCH + c];
    else if (row < 2 * HC) val = Wv[(ch + row - HC) * CCH + c];
    else                   val = Wq[(ch + row - 2 * HC) * CCH + c];
    Wb[idx] = f2fp8(val * 64.f);
  }
  if (idx < NHEADS * 96) {
    int row = idx % 96, h = idx / 96, ch = h * HC;
    float val;
    if (row < HC)          val = bk[ch + row];
    else if (row < 2 * HC) val = bv[ch + row - HC];
    else                   val = bq[ch + row - 2 * HC];
    bb[idx] = val;
  }
  if (idx < NB * NHEADS * HC * HC) ctx[idx] = 0.f;
  if (idx < NB * NHEADS * HC)      S[idx]   = 0.f;
}

// ---------------- kernel 0b: x [n][c][l] f32 -> xT [n][l][c] fp8 ----------------
__global__ __launch_bounds__(256)
void k_transpose(const float* __restrict__ x, unsigned char* __restrict__ xT) {
  __shared__ float tile[64][65];
  int b = blockIdx.x;
  int ct = b & 3;
  int lt = (b >> 2) & 255;
  int n  = b >> 10;
  int c0 = ct * 64, l0 = lt * 64;
  int t = threadIdx.x;
  int li = t & 63, cr = t >> 6;
  const float* xp = x + (size_t)n * CCH * LSP;
#pragma unroll
  for (int i = 0; i < 16; ++i) {
    int ci = cr * 16 + i;
    tile[ci][li] = xp[(size_t)(c0 + ci) * LSP + l0 + li];
  }
  __syncthreads();
  int cq = t & 15, lg = t >> 4;
  unsigned char* xo = xT + ((size_t)n * LSP + l0) * CCH + c0;
#pragma unroll
  for (int i = 0; i < 4; ++i) {
    int l = lg * 4 + i;
    unsigned pk = cvt4_fp8(tile[cq * 4][l], tile[cq * 4 + 1][l],
                           tile[cq * 4 + 2][l], tile[cq * 4 + 3][l]);
    *(unsigned*)&xo[(size_t)l * CCH + cq * 4] = pk;
  }
}

// ---------------- kernel 1: fused QKV, 2 blocks/CU, W frags in registers ----------------
// grid 512 = 8h x 8n x 8g; bid = h*64 + n*8 + g -> h-siblings differ by 64 (mult of 8)
// -> same XCD (x L2-shared). 4 waves = rh{0,1} x pq{0,1}; wave tile 48 rows x 32 px.
// W frags loaded to regs once (24 b64 = 48 VGPR) -> K-loop reads only 2 x-frags/kk.
// rh0 rows 0-47: k(32)+v(0-15) swapped mfma(x,W); rh1: v(16-31) swapped + q(32) normal.
__global__ __launch_bounds__(256)
void k_fused(const unsigned char* __restrict__ xT,
             const unsigned char* __restrict__ Wb, const float* __restrict__ bb,
             unsigned char* __restrict__ qbuf, float* __restrict__ ctx,
             float* __restrict__ S) {
  __shared__ unsigned char wlds[96 * 256];        // 24 KiB (staged once)
  __shared__ unsigned char xt[2][64 * 256];       // 32 KiB dbuf
  __shared__ unsigned short ekst[2][32][72];      // 9 KiB exp(k) strips, dbuf
  __shared__ unsigned short vst[2][32][72];       // 9 KiB v strips, dbuf

  int bid = (int)blockIdx.x;
  int h = bid >> 6;
  int r6 = bid & 63;
  int n = r6 >> 3, g = r6 & 7;
  int l0 = g << 11;                  // 2048-px range
  int nh = n * NHEADS + h;
  int tid = threadIdx.x;
  int wid = tid >> 6, lane = tid & 63;
  int r16 = lane & 15, kg = lane >> 4;
  int rh = wid >> 1;          // row half (48 rows)
  int pq = wid & 1;           // px half (32 px)

  const unsigned char* xTn = xT + ((size_t)n << 14) * CCH;
  const unsigned char* Wh = Wb + (size_t)h * 96 * CCH;

  // stage 64px x 256ch fp8 tile: 16 x 1KiB pieces, 4/wave; dest linear,
  // source 16B-chunk XOR (3-bit involution, rule 21)
  auto stage_xt = [&](int buf, int tt) {
    int lb = l0 + tt * 64;
#pragma unroll
    for (int i = 0; i < 4; ++i) {
      int p = wid * 4 + i;                   // 0..15
      int px = p * 4 + (lane >> 4);
      int c16 = lane & 15;
      gload_lds16(xTn + ((size_t)(lb + px) << 8) + ((c16 ^ (px & 7)) << 4),
                  &xt[buf][p * 1024]);
    }
  };

  // prologue: W (24 pieces, 6/wave) + tiles 0,1
#pragma unroll
  for (int i = 0; i < 6; ++i) {
    int p = wid * 6 + i;
    int row = p * 4 + (lane >> 4);
    int c16 = lane & 15;
    gload_lds16(Wh + ((size_t)row << 8) + ((c16 ^ (row & 7)) << 4), &wlds[p * 1024]);
  }
  stage_xt(0, 0);
  stage_xt(1, 1);

  float bw[3];
#pragma unroll
  for (int m = 0; m < 3; ++m) bw[m] = bb[h * 96 + rh * 48 + m * 16 + r16];
  float bq[2][4];
#pragma unroll
  for (int m = 0; m < 2; ++m)
#pragma unroll
    for (int r = 0; r < 4; ++r) bq[m][r] = bb[h * 96 + 64 + m * 16 + kg * 4 + r];

  f32x4 actx = {0.f, 0.f, 0.f, 0.f};   // quadrant (ckf=rh, cvf=pq), K = full 64 px
  float sk0 = 0.f, sk1 = 0.f;

  asm volatile("s_waitcnt vmcnt(4)" ::: "memory");   // W + tile0 done; tile1 in flight
  __builtin_amdgcn_sched_barrier(0);
  __builtin_amdgcn_s_barrier();
  __builtin_amdgcn_sched_barrier(0);

  const int base_w = (rh * 48 + r16) * 256;
  const int base_x = (pq * 32 + r16) * 256;

  // ---- W fragments -> registers, once (24 ds_read_b64 = 48 VGPR) ----
  ll wf[3][8];
#pragma unroll
  for (int m = 0; m < 3; ++m)
#pragma unroll
    for (int kk = 0; kk < 8; ++kk) {
      int sw = (((kk * 2 + (kg >> 1)) ^ (r16 & 7)) << 4) + ((kg & 1) << 3);
      wf[m][kk] = *(const ll*)&wlds[base_w + m * 4096 + sw];
    }

  for (int t = 0; t < NT; ++t) {
    int cur = t & 1, sb = t & 1, pb = sb ^ 1;
    // ---- ctx MFMA on previous tile's strips (bf16, one tile behind) ----
    if (t) {
#pragma unroll
      for (int ks = 0; ks < 2; ++ks) {
        int col = ks * 32 + kg * 8;
        short8 a = *(const short8*)&ekst[pb][rh * 16 + r16][col];
        short8 b = *(const short8*)&vst[pb][pq * 16 + r16][col];
        actx = __builtin_amdgcn_mfma_f32_16x16x32_bf16(a, b, actx, 0, 0, 0);
      }
    }
    // ---- K-loop: 48 rows x 32 px; only 2 x-frag b64 reads per kk ----
    f32x4 acc[3][2];
#pragma unroll
    for (int m = 0; m < 3; ++m) { acc[m][0] = (f32x4){0,0,0,0}; acc[m][1] = (f32x4){0,0,0,0}; }
    const unsigned char* xb = &xt[cur][0];
#pragma unroll
    for (int kk = 0; kk < 8; ++kk) {
      int sw = (((kk * 2 + (kg >> 1)) ^ (r16 & 7)) << 4) + ((kg & 1) << 3);
      ll xf0 = *(const ll*)&xb[base_x + sw];
      ll xf1 = *(const ll*)&xb[base_x + 4096 + sw];
      if (rh == 0) {
        acc[0][0] = __builtin_amdgcn_mfma_f32_16x16x32_fp8_fp8(xf0, wf[0][kk], acc[0][0], 0, 0, 0);
        acc[0][1] = __builtin_amdgcn_mfma_f32_16x16x32_fp8_fp8(xf1, wf[0][kk], acc[0][1], 0, 0, 0);
        acc[1][0] = __builtin_amdgcn_mfma_f32_16x16x32_fp8_fp8(xf0, wf[1][kk], acc[1][0], 0, 0, 0);
        acc[1][1] = __builtin_amdgcn_mfma_f32_16x16x32_fp8_fp8(xf1, wf[1][kk], acc[1][1], 0, 0, 0);
        acc[2][0] = __builtin_amdgcn_mfma_f32_16x16x32_fp8_fp8(xf0, wf[2][kk], acc[2][0], 0, 0, 0);
        acc[2][1] = __builtin_amdgcn_mfma_f32_16x16x32_fp8_fp8(xf1, wf[2][kk], acc[2][1], 0, 0, 0);
      } else {
        acc[0][0] = __builtin_amdgcn_mfma_f32_16x16x32_fp8_fp8(xf0, wf[0][kk], acc[0][0], 0, 0, 0);
        acc[0][1] = __builtin_amdgcn_mfma_f32_16x16x32_fp8_fp8(xf1, wf[0][kk], acc[0][1], 0, 0, 0);
        acc[1][0] = __builtin_amdgcn_mfma_f32_16x16x32_fp8_fp8(wf[1][kk], xf0, acc[1][0], 0, 0, 0);
        acc[1][1] = __builtin_amdgcn_mfma_f32_16x16x32_fp8_fp8(wf[1][kk], xf1, acc[1][1], 0, 0, 0);
        acc[2][0] = __builtin_amdgcn_mfma_f32_16x16x32_fp8_fp8(wf[2][kk], xf0, acc[2][0], 0, 0, 0);
        acc[2][1] = __builtin_amdgcn_mfma_f32_16x16x32_fp8_fp8(wf[2][kk], xf1, acc[2][1], 0, 0, 0);
      }
    }
    __builtin_amdgcn_s_barrier();          // barrier1: all waves done reading xt[cur]
    if (t + 2 < NT) stage_xt(cur, t + 2);  // refill freed buffer; full-tile DMA window

    // ---- epilogue (wave-local); acc * 1/64 undoes W pre-scale ----
    if (rh == 0) {
#pragma unroll
      for (int nf = 0; nf < 2; ++nf) {
        int col = pq * 32 + nf * 16 + kg * 4;
#pragma unroll
        for (int m = 0; m < 2; ++m) {       // k rows -> exp strips + S
          float e0 = __expf(acc[m][nf][0] * WSC + bw[m]);
          float e1 = __expf(acc[m][nf][1] * WSC + bw[m]);
          float e2 = __expf(acc[m][nf][2] * WSC + bw[m]);
          float e3 = __expf(acc[m][nf][3] * WSC + bw[m]);
          if (m == 0) sk0 += e0 + e1 + e2 + e3; else sk1 += e0 + e1 + e2 + e3;
          uint2 u = {cvt_pk_bf16(e0, e1), cvt_pk_bf16(e2, e3)};
          *(uint2*)&ekst[sb][m * 16 + r16][col] = u;
        }
        {                                    // v rows 0-15
          float v0 = acc[2][nf][0] * WSC + bw[2], v1 = acc[2][nf][1] * WSC + bw[2];
          float v2 = acc[2][nf][2] * WSC + bw[2], v3 = acc[2][nf][3] * WSC + bw[2];
          uint2 u = {cvt_pk_bf16(v0, v1), cvt_pk_bf16(v2, v3)};
          *(uint2*)&vst[sb][r16][col] = u;
        }
      }
    } else {
#pragma unroll
      for (int nf = 0; nf < 2; ++nf) {
        int col = pq * 32 + nf * 16 + kg * 4;
        {                                    // v rows 16-31
          float v0 = acc[0][nf][0] * WSC + bw[0], v1 = acc[0][nf][1] * WSC + bw[0];
          float v2 = acc[0][nf][2] * WSC + bw[0], v3 = acc[0][nf][3] * WSC + bw[0];
          uint2 u = {cvt_pk_bf16(v0, v1), cvt_pk_bf16(v2, v3)};
          *(uint2*)&vst[sb][16 + r16][col] = u;
        }
        // q: softmax over 32 ck, wholly in-wave (8 in-lane + shfl 16,32); store fp8
        float ea[4], eb[4];
        float s = 0.f;
#pragma unroll
        for (int r = 0; r < 4; ++r) {
          ea[r] = __expf(acc[1][nf][r] * WSC + bq[0][r]);
          eb[r] = __expf(acc[2][nf][r] * WSC + bq[1][r]);
          s += ea[r] + eb[r];
        }
        s += __shfl_xor(s, 16);
        s += __shfl_xor(s, 32);
        float inv = 1.f / s;
        int l = l0 + t * 64 + pq * 32 + nf * 16 + r16;
        unsigned char* qb = qbuf + (((size_t)nh * LSP + l) << 5);
        unsigned u0 = cvt4_fp8(ea[0] * inv, ea[1] * inv, ea[2] * inv, ea[3] * inv);
        unsigned u1 = cvt4_fp8(eb[0] * inv, eb[1] * inv, eb[2] * inv, eb[3] * inv);
        *(unsigned*)&qb[kg * 4]      = u0;
        *(unsigned*)&qb[16 + kg * 4] = u1;
      }
    }
    // barrier2: strips visible; next tile's buffer staged (counted, per-role)
    asm volatile("s_waitcnt lgkmcnt(0)" ::: "memory");
    __builtin_amdgcn_sched_barrier(0);
    if (t < NT - 2) {
      if (rh == 0) { asm volatile("s_waitcnt vmcnt(4)" ::: "memory"); }
      else         { asm volatile("s_waitcnt vmcnt(8)" ::: "memory"); }
    } else if (t == NT - 2) {
      if (rh == 0) { asm volatile("s_waitcnt vmcnt(0)" ::: "memory"); }
      else         { asm volatile("s_waitcnt vmcnt(4)" ::: "memory"); }
    }
    __builtin_amdgcn_sched_barrier(0);
    __builtin_amdgcn_s_barrier();
    __builtin_amdgcn_sched_barrier(0);
  }

  // final ctx on last tile's strips
#pragma unroll
  for (int ks = 0; ks < 2; ++ks) {
    int col = ks * 32 + kg * 8;
    short8 a = *(const short8*)&ekst[(NT - 1) & 1][rh * 16 + r16][col];
    short8 b = *(const short8*)&vst[(NT - 1) & 1][pq * 16 + r16][col];
    actx = __builtin_amdgcn_mfma_f32_16x16x32_bf16(a, b, actx, 0, 0, 0);
  }
  // flush: ctx quadrant + S rows
  float* cp = ctx + ((size_t)nh << 10);
#pragma unroll
  for (int r = 0; r < 4; ++r)
    atomicAdd(&cp[(rh * 16 + kg * 4 + r) * HC + pq * 16 + r16], actx[r]);
  if (rh == 0) {
    float s0 = sk0, s1 = sk1;
    s0 += __shfl_xor(s0, 16); s0 += __shfl_xor(s0, 32);
    s1 += __shfl_xor(s1, 16); s1 += __shfl_xor(s1, 32);
    if (kg == 0) {
      atomicAdd(&S[nh * HC + r16], s0);
      atomicAdd(&S[nh * HC + 16 + r16], s1);
    }
  }
}

// ---------------- kernel 2: ctx/S, transpose, -> fp8 ----------------
__global__ void k_norm(const float* __restrict__ ctx, const float* __restrict__ S,
                       unsigned char* __restrict__ ctxT) {
  int idx = blockIdx.x * 256 + threadIdx.x;  // 65536 = [n][h][ck][cv]
  int cv = idx & 31, ck = (idx >> 5) & 31, nh = idx >> 10;
  float v = ctx[idx] / S[(nh << 5) + ck];
  ctxT[(nh << 10) + (cv << 5) + ck] = f2fp8(v);
}

// ---------------- kernel 3: att = ctxT (fp8) x q_soft (fp8) + residual ----------------
__global__ __launch_bounds__(256)
void k_att(const float* __restrict__ x, const unsigned char* __restrict__ qbuf,
           const unsigned char* __restrict__ ctxT, float* __restrict__ out) {
  int b = blockIdx.x;
  int lc = b & 63;
  int nh = b >> 6;
  int h = nh & 7, n = nh >> 3;
  int tid = threadIdx.x, wid = tid >> 6, lane = tid & 63;
  int r16 = lane & 15, kg = lane >> 4;
  int lw = lc * 256 + wid * 64;

  const unsigned char* cp = ctxT + ((size_t)nh << 10);
  ll a0 = *(const ll*)&cp[(r16 << 5) + kg * 8];          // A[cv][ck], cv 0-15
  ll a1 = *(const ll*)&cp[((16 + r16) << 5) + kg * 8];   // cv 16-31
  const unsigned char* qb = qbuf + (((size_t)nh * LSP) << 5);
  const float* xp = x   + ((size_t)n * CCH + (size_t)h * HC) * LSP;
  float*       op = out + ((size_t)n * CCH + (size_t)h * HC) * LSP;

#pragma unroll
  for (int t = 0; t < 4; ++t) {
    int l = lw + t * 16;
    ll bq = *(const ll*)&qb[((size_t)(l + r16) << 5) + kg * 8];  // softmaxed q [l][ck] fp8
    f32x4 d0 = {0, 0, 0, 0}, d1 = {0, 0, 0, 0};
    d0 = __builtin_amdgcn_mfma_f32_16x16x32_fp8_fp8(a0, bq, d0, 0, 0, 0);
    d1 = __builtin_amdgcn_mfma_f32_16x16x32_fp8_fp8(a1, bq, d1, 0, 0, 0);
#pragma unroll
    for (int r = 0; r < 4; ++r) {
      int cv = kg * 4 + r;
      int li = l + r16;
      op[(size_t)cv * LSP + li]        = d0[r] + xp[(size_t)cv * LSP + li];
      op[(size_t)(cv + 16) * LSP + li] = d1[r] + xp[(size_t)(cv + 16) * LSP + li];
    }
  }
}

extern "C" void kernel_launch(void* const* d_in, const int* in_sizes, int n_in,
                              void* d_out, int out_size, void* d_ws, size_t ws_size,
                              hipStream_t stream) {
  (void)in_sizes; (void)n_in; (void)out_size; (void)ws_size;
  const float* x  = (const float*)d_in[0];
  const float* Wk = (const float*)d_in[1];
  const float* bk = (const float*)d_in[2];
  const float* Wq = (const float*)d_in[3];
  const float* bq = (const float*)d_in[4];
  const float* Wv = (const float*)d_in[5];
  const float* bv = (const float*)d_in[6];
  float* out = (float*)d_out;

  char* ws = (char*)d_ws;
  unsigned char*  Wb   = (unsigned char*)(ws + 0);           //    196608 (fp8, x64-scaled)
  float*          bbp  = (float*)(ws + 196608);              //      3072
  float*          ctx  = (float*)(ws + 199680);              //    262144
  unsigned char*  ctxT = (unsigned char*)(ws + 461824);      //     32768 (fp8)
  float*          S    = (float*)(ws + 494592);              //      8192
  unsigned char*  qbuf = (unsigned char*)(ws + 502784);      //  33554432 (fp8)
  unsigned char*  xT   = (unsigned char*)(ws + 34057216);    //  33554432 (fp8) -> 67611648

  k_prep<<<768, 256, 0, stream>>>(Wk, bk, Wq, bq, Wv, bv, Wb, bbp, ctx, S);
  k_transpose<<<NB * 256 * 4, 256, 0, stream>>>(x, xT);
  k_fused<<<512, 256, 0, stream>>>(xT, Wb, bbp, qbuf, ctx, S);
  k_norm<<<256, 256, 0, stream>>>(ctx, S, ctxT);
  k_att<<<NB * NHEADS * 64, 256, 0, stream>>>(x, qbuf, ctxT, out);
}